// Round 1
// baseline (551.740 us; speedup 1.0000x reference)
//
#include <hip/hip_runtime.h>
#include <cstdint>
#include <cstddef>

typedef _Float16 f16;
typedef __attribute__((ext_vector_type(2))) _Float16 f16x2;
typedef __attribute__((ext_vector_type(4))) _Float16 f16x4;
typedef __attribute__((ext_vector_type(8))) _Float16 f16x8;
typedef __attribute__((ext_vector_type(4))) float f32x4;

#define MFMA_16x16x32(a,b,c) __builtin_amdgcn_mfma_f32_16x16x32_f16((a),(b),(c),0,0,0)
#define MFMA_16x16x16(a,b,c) __builtin_amdgcn_mfma_f32_16x16x16f16((a),(b),(c),0,0,0)

#define NSEQ 384
#define CIN 128
#define NH 4
#define DHD 32
#define RNK 96
#define SDIM 449
#define MHID 256
#define NN (NSEQ*NSEQ)

// ---------------- weight conversion: W4T[col][k] = W*[k][col&127] (f16), WoT[c][hd] = Wo[hd][c]
__global__ __launch_bounds__(256) void k_convert(const float* __restrict__ Wq, const float* __restrict__ Wk,
    const float* __restrict__ Wv, const float* __restrict__ Wg, const float* __restrict__ Wo,
    f16* __restrict__ W4T, f16* __restrict__ WoT) {
  int idx = blockIdx.x*256 + threadIdx.x;   // 0..81919 (640*128)
  int c = idx >> 7, kk = idx & 127;
  if (c < 512) {
    int mat = c >> 7, cc = c & 127;
    const float* src = mat==0 ? Wq : (mat==1 ? Wk : (mat==2 ? Wv : Wg));
    W4T[c*CIN + kk] = (f16)src[kk*CIN + cc];
  } else {
    int cc = c - 512;
    WoT[cc*CIN + kk] = (f16)Wo[kk*CIN + cc];
  }
}

// ---------------- layernorm + row means (mean over axis 1) + f16 cast
__global__ __launch_bounds__(256) void k_ln(const float* __restrict__ x, const float* __restrict__ gamma,
    const float* __restrict__ beta, f16* __restrict__ xn, float* __restrict__ rowm) {
  int i = blockIdx.x; int t = threadIdx.x; int wave = t >> 6; int lane = t & 63;
  int c0 = lane*2;
  __shared__ float racc[CIN];
  if (t < CIN) racc[t] = 0.f;
  float g0 = gamma[c0], g1 = gamma[c0+1], be0 = beta[c0], be1 = beta[c0+1];
  float a0 = 0.f, a1 = 0.f;
  __syncthreads();
  for (int j = wave; j < NSEQ; j += 4) {
    const float2 v = *(const float2*)&x[(size_t)(i*NSEQ + j)*CIN + c0];
    float s = v.x + v.y, ss = v.x*v.x + v.y*v.y;
#pragma unroll
    for (int off = 32; off >= 1; off >>= 1) { s += __shfl_xor(s, off); ss += __shfl_xor(ss, off); }
    float mean = s * (1.0f/CIN);
    float var = ss * (1.0f/CIN) - mean*mean;
    float rs = rsqrtf(var + 1e-5f);
    float y0 = (v.x - mean)*rs*g0 + be0;
    float y1 = (v.y - mean)*rs*g1 + be1;
    f16x2 w; w[0] = (f16)y0; w[1] = (f16)y1;
    *(f16x2*)&xn[(size_t)(i*NSEQ + j)*CIN + c0] = w;
    a0 += y0; a1 += y1;
  }
  atomicAdd(&racc[c0], a0);
  atomicAdd(&racc[c0+1], a1);
  __syncthreads();
  if (t < CIN) rowm[i*CIN + t] = racc[t] * (1.0f/NSEQ);
}

// ---------------- column means (mean over axis 0) from f16 xn
__global__ __launch_bounds__(256) void k_colmean(const f16* __restrict__ xn, float* __restrict__ colm) {
  int j = blockIdx.x; int t = threadIdx.x;
  int c = t & 127, half = t >> 7;
  float acc = 0.f;
  int i0 = half*192;
#pragma unroll 4
  for (int ii = i0; ii < i0 + 192; ++ii)
    acc += (float)xn[(size_t)(ii*NSEQ + j)*CIN + c];
  __shared__ float sb[256];
  sb[t] = acc;
  __syncthreads();
  if (t < 128) colm[j*CIN + t] = (sb[t] + sb[t+128]) * (1.0f/NSEQ);
}

// ---------------- bias MLPs: 4 rows per block; writes transposed qbT/kbT[o][row], o = h*96+r
__global__ __launch_bounds__(256) void k_mlp(const float* __restrict__ rowm, const float* __restrict__ colm,
    const float* __restrict__ sinp, const float* __restrict__ W1q, const float* __restrict__ W2q,
    const float* __restrict__ W3q, const float* __restrict__ W1k, const float* __restrict__ W2k,
    const float* __restrict__ W3k, float* __restrict__ qbT, float* __restrict__ kbT) {
  int b = blockIdx.x, t = threadIdx.x;
  bool isQ = b < 96;
  int r0 = (isQ ? b : b - 96) * 4;
  const float* mean = isQ ? rowm : colm;
  const float* W1 = isQ ? W1q : W1k;
  const float* W2 = isQ ? W2q : W2k;
  const float* W3 = isQ ? W3q : W3k;
  float* outp = isQ ? qbT : kbT;
  const int ZD = SDIM + CIN;  // 577
  __shared__ float z[4][SDIM + CIN];
  __shared__ float h1[4][MHID];
  __shared__ float h2[4][MHID];
  for (int idx = t; idx < 4*ZD; idx += 256) {
    int rr = idx / ZD, u = idx - rr*ZD;
    z[rr][u] = (u < CIN) ? mean[(r0+rr)*CIN + u] : sinp[(r0+rr)*SDIM + (u - CIN)];
  }
  __syncthreads();
  {
    float a0=0,a1=0,a2=0,a3=0;
    for (int u = 0; u < ZD; ++u) {
      float wv = W1[u*MHID + t];
      a0 += z[0][u]*wv; a1 += z[1][u]*wv; a2 += z[2][u]*wv; a3 += z[3][u]*wv;
    }
    h1[0][t]=tanhf(a0); h1[1][t]=tanhf(a1); h1[2][t]=tanhf(a2); h1[3][t]=tanhf(a3);
  }
  __syncthreads();
  {
    float a0=0,a1=0,a2=0,a3=0;
    for (int u = 0; u < MHID; ++u) {
      float wv = W2[u*MHID + t];
      a0 += h1[0][u]*wv; a1 += h1[1][u]*wv; a2 += h1[2][u]*wv; a3 += h1[3][u]*wv;
    }
    h2[0][t]=tanhf(a0); h2[1][t]=tanhf(a1); h2[2][t]=tanhf(a2); h2[3][t]=tanhf(a3);
  }
  __syncthreads();
  {
    float a0=0,a1=0,a2=0,a3=0;
    for (int u = 0; u < MHID; ++u) {
      float wv = W3[u*(NH*RNK) + t];
      a0 += h2[0][u]*wv; a1 += h2[1][u]*wv; a2 += h2[2][u]*wv; a3 += h2[3][u]*wv;
    }
    outp[t*NSEQ + r0+0]=a0; outp[t*NSEQ + r0+1]=a1; outp[t*NSEQ + r0+2]=a2; outp[t*NSEQ + r0+3]=a3;
  }
  if (t < 128) {
    int o2 = t + 256;
    float a0=0,a1=0,a2=0,a3=0;
    for (int u = 0; u < MHID; ++u) {
      float wv = W3[u*(NH*RNK) + o2];
      a0 += h2[0][u]*wv; a1 += h2[1][u]*wv; a2 += h2[2][u]*wv; a3 += h2[3][u]*wv;
    }
    outp[o2*NSEQ + r0+0]=a0; outp[o2*NSEQ + r0+1]=a1; outp[o2*NSEQ + r0+2]=a2; outp[o2*NSEQ + r0+3]=a3;
  }
}

// ---------------- low-rank bias outer product: BiasT[h][k][q] (f16)
__global__ __launch_bounds__(128) void k_bias(const float* __restrict__ qbT, const float* __restrict__ kbT,
    f16* __restrict__ biasT) {
  int b = blockIdx.x;            // h*NSEQ + kk
  int h = b / NSEQ, kk = b - h*NSEQ;
  int t = threadIdx.x;
  __shared__ float kr[RNK];
  if (t < RNK) kr[t] = kbT[(h*RNK + t)*NSEQ + kk];
  __syncthreads();
  float a0=0,a1=0,a2=0;
  for (int r = 0; r < RNK; ++r) {
    float kv = kr[r];
    const float* qrow = qbT + (h*RNK + r)*NSEQ;
    a0 += kv*qrow[t]; a1 += kv*qrow[t+128]; a2 += kv*qrow[t+256];
  }
  f16* dst = biasT + (size_t)(h*NSEQ + kk)*NSEQ;
  dst[t] = (f16)a0; dst[t+128] = (f16)a1; dst[t+256] = (f16)a2;
}

// ---------------- projections: xn @ [Wq|Wk|Wv|Wg] -> q,k,v ([i,h,n,d] f16, q scaled), g ([i*N+j, hd])
__global__ __launch_bounds__(256) void k_proj(const f16* __restrict__ xn, const f16* __restrict__ W4T,
    const float* __restrict__ bg, f16* __restrict__ qb, f16* __restrict__ kb, f16* __restrict__ vb,
    f16* __restrict__ gb) {
  int b = blockIdx.x; int mb = b >> 2, nb = b & 3;
  int t = threadIdx.x, wave = t >> 6, lane = t & 63;
  int l15 = lane & 15, quad = lane >> 4;
  __shared__ __align__(16) f16 As[128*128];  // XOR-swizzled chunks of 8 f16
  __shared__ __align__(16) f16 Bs[128*128];
  int Mbase = mb*128;
  for (int p = 0; p < 8; ++p) {
    int c = p*256 + t; int row = c >> 4, ci = c & 15;
    int sw = (ci ^ (row & 15)) * 8;
    *(f16x8*)&As[row*128 + sw] = *(const f16x8*)&xn[(size_t)(Mbase + row)*CIN + ci*8];
    *(f16x8*)&Bs[row*128 + sw] = *(const f16x8*)&W4T[(size_t)(nb*128 + row)*CIN + ci*8];
  }
  __syncthreads();
  int m0 = wave*32;
  f16x8 af[2][4];
#pragma unroll
  for (int mt = 0; mt < 2; ++mt)
#pragma unroll
    for (int kt = 0; kt < 4; ++kt)
      af[mt][kt] = *(const f16x8*)&As[(m0 + mt*16 + l15)*128 + ((kt*4 + quad) ^ l15)*8];
  int i = mb/3, j0 = (mb - (mb/3)*3)*128 + m0;
#pragma unroll
  for (int ct = 0; ct < 8; ++ct) {
    f32x4 acc0 = (f32x4){0,0,0,0}, acc1 = (f32x4){0,0,0,0};
#pragma unroll
    for (int kt = 0; kt < 4; ++kt) {
      f16x8 bf = *(const f16x8*)&Bs[(ct*16 + l15)*128 + ((kt*4 + quad) ^ l15)*8];
      acc0 = MFMA_16x16x32(af[0][kt], bf, acc0);
      acc1 = MFMA_16x16x32(af[1][kt], bf, acc1);
    }
    int col = nb*128 + ct*16 + l15;
    int cc = col & 127;
    int hh = cc >> 5, d = cc & 31;
    if (nb == 3) {
      float bgv = bg[cc];
#pragma unroll
      for (int mt = 0; mt < 2; ++mt) {
        f32x4 a = mt ? acc1 : acc0;
#pragma unroll
        for (int r = 0; r < 4; ++r) {
          int jj = j0 + mt*16 + quad*4 + r;
          float sg = 1.0f/(1.0f + __expf(-(a[r] + bgv)));
          gb[(size_t)(i*NSEQ + jj)*CIN + cc] = (f16)sg;
        }
      }
    } else {
      f16* dstb = nb==0 ? qb : (nb==1 ? kb : vb);
      float scale = nb==0 ? 0.17677669529663687f : 1.0f;
#pragma unroll
      for (int mt = 0; mt < 2; ++mt) {
        f32x4 a = mt ? acc1 : acc0;
#pragma unroll
        for (int r = 0; r < 4; ++r) {
          int jj = j0 + mt*16 + quad*4 + r;
          dstb[((size_t)(i*NH + hh)*NSEQ + jj)*DHD + d] = (f16)(a[r]*scale);
        }
      }
    }
  }
}

// ---------------- attention: one block per (i, h). S^T = K.Q^T + bias (MFMA C-init),
// no-max softmax (scores are tiny), P stays in registers as A-operand for P.V.
__global__ __launch_bounds__(256) void k_attn(const f16* __restrict__ qg, const f16* __restrict__ kg,
    const f16* __restrict__ vg, const f16* __restrict__ biasT, f16* __restrict__ og) {
  int b = blockIdx.x; int h = b & 3; int i = b >> 2;
  int t = threadIdx.x; int wave = t >> 6; int lane = t & 63;
  int l15 = lane & 15, quad = lane >> 4;
  __shared__ __align__(16) f16 Ks[NSEQ*40];  // stride 40 f16 = 80 B (2-way max)
  __shared__ __align__(16) f16 Vs[NSEQ*36];  // stride 36 f16 = 72 B (conflict-free u16 reads)
  size_t base = (size_t)(i*NH + h) * NSEQ * DHD;
  for (int p = 0; p < 6; ++p) {
    int c = p*256 + t; int row = c >> 2, ci = c & 3;
    *(f16x8*)&Ks[row*40 + ci*8] = *(const f16x8*)&kg[base + row*DHD + ci*8];
  }
  for (int p = 0; p < 12; ++p) {
    int c = p*256 + t; int row = c >> 3, ci = c & 7;
    *(f16x4*)&Vs[row*36 + ci*4] = *(const f16x4*)&vg[base + row*DHD + ci*4];
  }
  int qt0 = wave*6;
  f16x8 qf[6];
#pragma unroll
  for (int s = 0; s < 6; ++s)
    qf[s] = *(const f16x8*)&qg[base + (size_t)((qt0+s)*16 + l15)*DHD + quad*8];
  f32x4 oa[6][2];
  float lsum[6];
#pragma unroll
  for (int s = 0; s < 6; ++s) { lsum[s] = 0.f; oa[s][0] = (f32x4){0,0,0,0}; oa[s][1] = (f32x4){0,0,0,0}; }
  __syncthreads();
  const f16* bb = biasT + (size_t)h*NSEQ*NSEQ;
  for (int kt = 0; kt < 24; ++kt) {
    f16x8 kf = *(const f16x8*)&Ks[(kt*16 + l15)*40 + quad*8];
    int vbase = (kt*16 + quad*4)*36 + l15;
    f16x4 vf0, vf1;
#pragma unroll
    for (int jj = 0; jj < 4; ++jj) { vf0[jj] = Vs[vbase + jj*36]; vf1[jj] = Vs[vbase + jj*36 + 16]; }
    const f16* bp = bb + (size_t)(kt*16 + quad*4)*NSEQ + l15;
    f32x4 cb[6];
#pragma unroll
    for (int s = 0; s < 6; ++s) {
      int qc = (qt0 + s)*16;
      cb[s][0] = (float)bp[qc];
      cb[s][1] = (float)bp[qc + NSEQ];
      cb[s][2] = (float)bp[qc + 2*NSEQ];
      cb[s][3] = (float)bp[qc + 3*NSEQ];
    }
#pragma unroll
    for (int s = 0; s < 6; ++s) {
      f32x4 st = MFMA_16x16x32(kf, qf[s], cb[s]);   // S^T tile: row=k, col=q, bias pre-added via C
      float p0 = __expf(st[0]), p1 = __expf(st[1]), p2 = __expf(st[2]), p3 = __expf(st[3]);
      lsum[s] += (p0 + p1) + (p2 + p3);
      f16x4 pa; pa[0]=(f16)p0; pa[1]=(f16)p1; pa[2]=(f16)p2; pa[3]=(f16)p3;
      oa[s][0] = MFMA_16x16x16(pa, vf0, oa[s][0]);  // C-layout of S^T == A-layout for K=16 MFMA
      oa[s][1] = MFMA_16x16x16(pa, vf1, oa[s][1]);
    }
  }
#pragma unroll
  for (int s = 0; s < 6; ++s) {
    float lf = lsum[s];
    lf += __shfl_xor(lf, 16);
    lf += __shfl_xor(lf, 32);
    float inv = 1.0f / lf;   // valid for q = l15
#pragma unroll
    for (int r = 0; r < 4; ++r) {
      float invr = __shfl(inv, quad*4 + r);
      int qrow = (qt0+s)*16 + quad*4 + r;
      size_t ob = (size_t)(i*NSEQ + qrow)*(NH*DHD) + h*DHD;
      og[ob + l15]      = (f16)(oa[s][0][r] * invr);
      og[ob + 16 + l15] = (f16)(oa[s][1][r] * invr);
    }
  }
}

// ---------------- final: out = (g*o) @ Wo + bo  (fp32 out)
__global__ __launch_bounds__(256) void k_final(const f16* __restrict__ gb, const f16* __restrict__ ob,
    const f16* __restrict__ WoT, const float* __restrict__ bo, float* __restrict__ out) {
  int mb = blockIdx.x;
  int t = threadIdx.x, wave = t >> 6, lane = t & 63;
  int l15 = lane & 15, quad = lane >> 4;
  __shared__ __align__(16) f16 As[128*128];
  __shared__ __align__(16) f16 Bs[128*128];
  int Mbase = mb*128;
  for (int p = 0; p < 8; ++p) {
    int c = p*256 + t; int row = c >> 4, ci = c & 15;
    int sw = (ci ^ (row & 15)) * 8;
    f16x8 gv = *(const f16x8*)&gb[(size_t)(Mbase + row)*CIN + ci*8];
    f16x8 ov = *(const f16x8*)&ob[(size_t)(Mbase + row)*CIN + ci*8];
    *(f16x8*)&As[row*128 + sw] = gv*ov;
    *(f16x8*)&Bs[row*128 + sw] = *(const f16x8*)&WoT[row*CIN + ci*8];
  }
  __syncthreads();
  int m0 = wave*32;
  f16x8 af[2][4];
#pragma unroll
  for (int mt = 0; mt < 2; ++mt)
#pragma unroll
    for (int kt = 0; kt < 4; ++kt)
      af[mt][kt] = *(const f16x8*)&As[(m0 + mt*16 + l15)*128 + ((kt*4 + quad) ^ l15)*8];
#pragma unroll
  for (int ct = 0; ct < 8; ++ct) {
    f32x4 acc0 = (f32x4){0,0,0,0}, acc1 = (f32x4){0,0,0,0};
#pragma unroll
    for (int kt = 0; kt < 4; ++kt) {
      f16x8 bf = *(const f16x8*)&Bs[(ct*16 + l15)*128 + ((kt*4 + quad) ^ l15)*8];
      acc0 = MFMA_16x16x32(af[0][kt], bf, acc0);
      acc1 = MFMA_16x16x32(af[1][kt], bf, acc1);
    }
    float bov = bo[ct*16 + l15];
#pragma unroll
    for (int mt = 0; mt < 2; ++mt) {
      f32x4 a = mt ? acc1 : acc0;
#pragma unroll
      for (int r = 0; r < 4; ++r) {
        int mrow = Mbase + m0 + mt*16 + quad*4 + r;
        out[(size_t)mrow*CIN + ct*16 + l15] = a[r] + bov;
      }
    }
  }
}

extern "C" void kernel_launch(void* const* d_in, const int* in_sizes, int n_in,
                              void* d_out, int out_size, void* d_ws, size_t ws_size,
                              hipStream_t stream) {
  (void)in_sizes; (void)n_in; (void)out_size; (void)ws_size;
  const float* x    = (const float*)d_in[0];
  const float* sinp = (const float*)d_in[1];
  const float* gam  = (const float*)d_in[2];
  const float* bet  = (const float*)d_in[3];
  const float* Wq1  = (const float*)d_in[4];
  const float* Wq2  = (const float*)d_in[5];
  const float* Wq3  = (const float*)d_in[6];
  const float* Wk1  = (const float*)d_in[7];
  const float* Wk2  = (const float*)d_in[8];
  const float* Wk3  = (const float*)d_in[9];
  const float* Wqa  = (const float*)d_in[10];
  const float* Wka  = (const float*)d_in[11];
  const float* Wva  = (const float*)d_in[12];
  const float* Wg   = (const float*)d_in[13];
  const float* bg   = (const float*)d_in[14];
  const float* Wo   = (const float*)d_in[15];
  const float* bo   = (const float*)d_in[16];
  float* out = (float*)d_out;

  char* w = (char*)d_ws;
  auto carve = [&](size_t bytes) { char* p = w; w += (bytes + 255) & ~(size_t)255; return p; };
  f16*   xn    = (f16*)carve((size_t)NN*CIN*2);    // reused as o after k_proj
  f16*   qb    = (f16*)carve((size_t)NN*CIN*2);
  f16*   kb    = (f16*)carve((size_t)NN*CIN*2);
  f16*   vb    = (f16*)carve((size_t)NN*CIN*2);
  f16*   gbuf  = (f16*)carve((size_t)NN*CIN*2);
  f16*   biasT = (f16*)carve((size_t)NH*NSEQ*NSEQ*2);
  float* rowm  = (float*)carve((size_t)NSEQ*CIN*4);
  float* colm  = (float*)carve((size_t)NSEQ*CIN*4);
  float* qbT   = (float*)carve((size_t)(NH*RNK)*NSEQ*4);
  float* kbT   = (float*)carve((size_t)(NH*RNK)*NSEQ*4);
  f16*   W4T   = (f16*)carve((size_t)512*CIN*2);
  f16*   WoT   = (f16*)carve((size_t)CIN*CIN*2);
  f16*   obuf  = xn;

  k_convert<<<320, 256, 0, stream>>>(Wqa, Wka, Wva, Wg, Wo, W4T, WoT);
  k_ln<<<NSEQ, 256, 0, stream>>>(x, gam, bet, xn, rowm);
  k_colmean<<<NSEQ, 256, 0, stream>>>(xn, colm);
  k_mlp<<<192, 256, 0, stream>>>(rowm, colm, sinp, Wq1, Wq2, Wq3, Wk1, Wk2, Wk3, qbT, kbT);
  k_bias<<<NH*NSEQ, 128, 0, stream>>>(qbT, kbT, biasT);
  k_proj<<<4608, 256, 0, stream>>>(xn, W4T, bg, qb, kb, vb, gbuf);
  k_attn<<<NH*NSEQ, 256, 0, stream>>>(qb, kb, vb, biasT, obuf);
  k_final<<<1152, 256, 0, stream>>>(gbuf, obuf, WoT, bo, out);
}

// Round 2
// 522.375 us; speedup vs baseline: 1.0562x; 1.0562x over previous
//
#include <hip/hip_runtime.h>
#include <cstdint>
#include <cstddef>

typedef _Float16 f16;
typedef __attribute__((ext_vector_type(2))) _Float16 f16x2;
typedef __attribute__((ext_vector_type(4))) _Float16 f16x4;
typedef __attribute__((ext_vector_type(8))) _Float16 f16x8;
typedef __attribute__((ext_vector_type(4))) float f32x4;

#define MFMA_16x16x32(a,b,c) __builtin_amdgcn_mfma_f32_16x16x32_f16((a),(b),(c),0,0,0)
#define MFMA_16x16x16(a,b,c) __builtin_amdgcn_mfma_f32_16x16x16f16((a),(b),(c),0,0,0)

#define NSEQ 384
#define CIN 128
#define NH 4
#define DHD 32
#define RNK 96
#define SDIM 449
#define MHID 256
#define NN (NSEQ*NSEQ)

#define KPAD 608            // 577 padded to 19*32
#define ZSTR 616            // LDS stride for z (2-way bank aliasing only)
#define HSTR 264            // LDS stride for h1/h2
// f16 transposed-weight pool offsets (elements)
#define OFF_W1 0
#define SZ_W1 (MHID*KPAD)          // 155648 per matrix
#define OFF_W2 (2*SZ_W1)           // 311296
#define SZ_W2 (MHID*MHID)          // 65536
#define OFF_W3 (OFF_W2 + 2*SZ_W2)  // 442368
#define SZ_W3 ((NH*RNK)*MHID)      // 98304
#define WMLP_TOT (OFF_W3 + 2*SZ_W3) // 638976

// ---------------- weight conversion: W4T[col][k] = W*[k][col&127] (f16), WoT[c][hd] = Wo[hd][c]
__global__ __launch_bounds__(256) void k_convert(const float* __restrict__ Wq, const float* __restrict__ Wk,
    const float* __restrict__ Wv, const float* __restrict__ Wg, const float* __restrict__ Wo,
    f16* __restrict__ W4T, f16* __restrict__ WoT) {
  int idx = blockIdx.x*256 + threadIdx.x;   // 0..81919 (640*128)
  int c = idx >> 7, kk = idx & 127;
  if (c < 512) {
    int mat = c >> 7, cc = c & 127;
    const float* src = mat==0 ? Wq : (mat==1 ? Wk : (mat==2 ? Wv : Wg));
    W4T[c*CIN + kk] = (f16)src[kk*CIN + cc];
  } else {
    int cc = c - 512;
    WoT[cc*CIN + kk] = (f16)Wo[kk*CIN + cc];
  }
}

// ---------------- MLP weight transpose+cast into one f16 pool (coalesced writes)
__global__ __launch_bounds__(256) void k_convert2(const float* __restrict__ Wq1, const float* __restrict__ Wq2,
    const float* __restrict__ Wq3, const float* __restrict__ Wk1, const float* __restrict__ Wk2,
    const float* __restrict__ Wk3, f16* __restrict__ wmlp) {
  int idx = blockIdx.x*256 + threadIdx.x;   // 0..638975
  float val;
  if (idx < OFF_W2) {
    int m = idx / SZ_W1, r = idx - m*SZ_W1;
    int c = r / KPAD, kk = r - c*KPAD;
    const float* src = m ? Wk1 : Wq1;
    val = (kk < SDIM + CIN) ? src[kk*MHID + c] : 0.f;
  } else if (idx < OFF_W3) {
    int r = idx - OFF_W2;
    int m = r >> 16, rr = r & 65535;
    int c = rr >> 8, kk = rr & 255;
    const float* src = m ? Wk2 : Wq2;
    val = src[kk*MHID + c];
  } else {
    int r = idx - OFF_W3;
    int m = r / SZ_W3, rr = r - m*SZ_W3;
    int c = rr >> 8, kk = rr & 255;
    const float* src = m ? Wk3 : Wq3;
    val = src[kk*(NH*RNK) + c];
  }
  wmlp[idx] = (f16)val;
}

// ---------------- layernorm + row means (mean over axis 1) + f16 cast
__global__ __launch_bounds__(256) void k_ln(const float* __restrict__ x, const float* __restrict__ gamma,
    const float* __restrict__ beta, f16* __restrict__ xn, float* __restrict__ rowm) {
  int i = blockIdx.x; int t = threadIdx.x; int wave = t >> 6; int lane = t & 63;
  int c0 = lane*2;
  __shared__ float racc[CIN];
  if (t < CIN) racc[t] = 0.f;
  float g0 = gamma[c0], g1 = gamma[c0+1], be0 = beta[c0], be1 = beta[c0+1];
  float a0 = 0.f, a1 = 0.f;
  __syncthreads();
  for (int j = wave; j < NSEQ; j += 4) {
    const float2 v = *(const float2*)&x[(size_t)(i*NSEQ + j)*CIN + c0];
    float s = v.x + v.y, ss = v.x*v.x + v.y*v.y;
#pragma unroll
    for (int off = 32; off >= 1; off >>= 1) { s += __shfl_xor(s, off); ss += __shfl_xor(ss, off); }
    float mean = s * (1.0f/CIN);
    float var = ss * (1.0f/CIN) - mean*mean;
    float rs = rsqrtf(var + 1e-5f);
    float y0 = (v.x - mean)*rs*g0 + be0;
    float y1 = (v.y - mean)*rs*g1 + be1;
    f16x2 w; w[0] = (f16)y0; w[1] = (f16)y1;
    *(f16x2*)&xn[(size_t)(i*NSEQ + j)*CIN + c0] = w;
    a0 += y0; a1 += y1;
  }
  atomicAdd(&racc[c0], a0);
  atomicAdd(&racc[c0+1], a1);
  __syncthreads();
  if (t < CIN) rowm[i*CIN + t] = racc[t] * (1.0f/NSEQ);
}

// ---------------- column means (mean over axis 0) from f16 xn
__global__ __launch_bounds__(256) void k_colmean(const f16* __restrict__ xn, float* __restrict__ colm) {
  int j = blockIdx.x; int t = threadIdx.x;
  int c = t & 127, half = t >> 7;
  float acc = 0.f;
  int i0 = half*192;
#pragma unroll 4
  for (int ii = i0; ii < i0 + 192; ++ii)
    acc += (float)xn[(size_t)(ii*NSEQ + j)*CIN + c];
  __shared__ float sb[256];
  sb[t] = acc;
  __syncthreads();
  if (t < 128) colm[j*CIN + t] = (sb[t] + sb[t+128]) * (1.0f/NSEQ);
}

// ---------------- fused bias MLP (MFMA): 32 rows/block, 3 layers block-local.
// writes transposed qbT/kbT[o][row] fp32, o = h*96+r
__global__ __launch_bounds__(256) void k_mlp2(const float* __restrict__ rowm, const float* __restrict__ colm,
    const float* __restrict__ sinp, const f16* __restrict__ wmlp,
    float* __restrict__ qbT, float* __restrict__ kbT) {
  int b = blockIdx.x;
  bool isQ = b < 12;
  int r0 = (isQ ? b : b - 12) * 32;
  const float* mean = isQ ? rowm : colm;
  const f16* W1T = wmlp + (isQ ? 0 : SZ_W1);
  const f16* W2T = wmlp + OFF_W2 + (isQ ? 0 : SZ_W2);
  const f16* W3T = wmlp + OFF_W3 + (isQ ? 0 : SZ_W3);
  float* outp = isQ ? qbT : kbT;
  int t = threadIdx.x, wave = t >> 6, lane = t & 63;
  int l15 = lane & 15, quad = lane >> 4;
  int rt = wave & 1, ch = wave >> 1;   // row-tile, col-half

  __shared__ __align__(16) f16 z[32*ZSTR];
  __shared__ __align__(16) f16 hbuf[2][32*HSTR];

  for (int idx = t; idx < 32*KPAD; idx += 256) {
    int row = idx / KPAD, u = idx - row*KPAD;
    float v;
    if (u < CIN) v = mean[(r0+row)*CIN + u];
    else if (u < CIN + SDIM) v = sinp[(r0+row)*SDIM + (u - CIN)];
    else v = 0.f;
    z[row*ZSTR + u] = (f16)v;
  }
  __syncthreads();

  // ---- layer 1: [32 x 608] @ W1T^T -> tanh -> h1 [32 x 256]
  {
    f32x4 acc[8];
#pragma unroll
    for (int c = 0; c < 8; ++c) acc[c] = (f32x4){0,0,0,0};
    for (int ks = 0; ks < 19; ++ks) {
      f16x8 af = *(const f16x8*)&z[(rt*16 + l15)*ZSTR + ks*32 + quad*8];
#pragma unroll
      for (int c = 0; c < 8; ++c) {
        f16x8 bf = *(const f16x8*)&W1T[(size_t)((ch*8 + c)*16 + l15)*KPAD + ks*32 + quad*8];
        acc[c] = MFMA_16x16x32(af, bf, acc[c]);
      }
    }
#pragma unroll
    for (int c = 0; c < 8; ++c) {
      int col = (ch*8 + c)*16 + l15;
#pragma unroll
      for (int r = 0; r < 4; ++r) {
        float th = 1.f - 2.f/(1.f + __expf(2.f*acc[c][r]));
        hbuf[0][(rt*16 + quad*4 + r)*HSTR + col] = (f16)th;
      }
    }
  }
  __syncthreads();

  // ---- layer 2: h1 @ W2T^T -> tanh -> h2 [32 x 256]
  {
    f32x4 acc[8];
#pragma unroll
    for (int c = 0; c < 8; ++c) acc[c] = (f32x4){0,0,0,0};
    for (int ks = 0; ks < 8; ++ks) {
      f16x8 af = *(const f16x8*)&hbuf[0][(rt*16 + l15)*HSTR + ks*32 + quad*8];
#pragma unroll
      for (int c = 0; c < 8; ++c) {
        f16x8 bf = *(const f16x8*)&W2T[(size_t)((ch*8 + c)*16 + l15)*MHID + ks*32 + quad*8];
        acc[c] = MFMA_16x16x32(af, bf, acc[c]);
      }
    }
#pragma unroll
    for (int c = 0; c < 8; ++c) {
      int col = (ch*8 + c)*16 + l15;
#pragma unroll
      for (int r = 0; r < 4; ++r) {
        float th = 1.f - 2.f/(1.f + __expf(2.f*acc[c][r]));
        hbuf[1][(rt*16 + quad*4 + r)*HSTR + col] = (f16)th;
      }
    }
  }
  __syncthreads();

  // ---- layer 3: h2 @ W3T^T -> [32 x 384] -> transposed fp32 store
  {
    f32x4 acc[12];
#pragma unroll
    for (int c = 0; c < 12; ++c) acc[c] = (f32x4){0,0,0,0};
    for (int ks = 0; ks < 8; ++ks) {
      f16x8 af = *(const f16x8*)&hbuf[1][(rt*16 + l15)*HSTR + ks*32 + quad*8];
#pragma unroll
      for (int c = 0; c < 12; ++c) {
        f16x8 bf = *(const f16x8*)&W3T[(size_t)((ch*12 + c)*16 + l15)*MHID + ks*32 + quad*8];
        acc[c] = MFMA_16x16x32(af, bf, acc[c]);
      }
    }
#pragma unroll
    for (int c = 0; c < 12; ++c) {
      int o = (ch*12 + c)*16 + l15;
#pragma unroll
      for (int r = 0; r < 4; ++r)
        outp[o*NSEQ + r0 + rt*16 + quad*4 + r] = acc[c][r];
    }
  }
}

// ---------------- low-rank bias outer product: BiasT[h][k][q] (f16)
__global__ __launch_bounds__(128) void k_bias(const float* __restrict__ qbT, const float* __restrict__ kbT,
    f16* __restrict__ biasT) {
  int b = blockIdx.x;            // h*NSEQ + kk
  int h = b / NSEQ, kk = b - h*NSEQ;
  int t = threadIdx.x;
  __shared__ float kr[RNK];
  if (t < RNK) kr[t] = kbT[(h*RNK + t)*NSEQ + kk];
  __syncthreads();
  float a0=0,a1=0,a2=0;
  for (int r = 0; r < RNK; ++r) {
    float kv = kr[r];
    const float* qrow = qbT + (h*RNK + r)*NSEQ;
    a0 += kv*qrow[t]; a1 += kv*qrow[t+128]; a2 += kv*qrow[t+256];
  }
  f16* dst = biasT + (size_t)(h*NSEQ + kk)*NSEQ;
  dst[t] = (f16)a0; dst[t+128] = (f16)a1; dst[t+256] = (f16)a2;
}

// ---------------- projections: xn @ [Wq|Wk|Wv|Wg] -> q,k,v ([i,h,n,d] f16, q scaled), g ([i*N+j, hd])
__global__ __launch_bounds__(256) void k_proj(const f16* __restrict__ xn, const f16* __restrict__ W4T,
    const float* __restrict__ bg, f16* __restrict__ qb, f16* __restrict__ kb, f16* __restrict__ vb,
    f16* __restrict__ gb) {
  int b = blockIdx.x; int mb = b >> 2, nb = b & 3;
  int t = threadIdx.x, wave = t >> 6, lane = t & 63;
  int l15 = lane & 15, quad = lane >> 4;
  __shared__ __align__(16) f16 As[128*128];  // XOR-swizzled chunks of 8 f16
  __shared__ __align__(16) f16 Bs[128*128];
  int Mbase = mb*128;
  for (int p = 0; p < 8; ++p) {
    int c = p*256 + t; int row = c >> 4, ci = c & 15;
    int sw = (ci ^ (row & 15)) * 8;
    *(f16x8*)&As[row*128 + sw] = *(const f16x8*)&xn[(size_t)(Mbase + row)*CIN + ci*8];
    *(f16x8*)&Bs[row*128 + sw] = *(const f16x8*)&W4T[(size_t)(nb*128 + row)*CIN + ci*8];
  }
  __syncthreads();
  int m0 = wave*32;
  f16x8 af[2][4];
#pragma unroll
  for (int mt = 0; mt < 2; ++mt)
#pragma unroll
    for (int kt = 0; kt < 4; ++kt)
      af[mt][kt] = *(const f16x8*)&As[(m0 + mt*16 + l15)*128 + ((kt*4 + quad) ^ l15)*8];
  int i = mb/3, j0 = (mb - (mb/3)*3)*128 + m0;
#pragma unroll
  for (int ct = 0; ct < 8; ++ct) {
    f32x4 acc0 = (f32x4){0,0,0,0}, acc1 = (f32x4){0,0,0,0};
#pragma unroll
    for (int kt = 0; kt < 4; ++kt) {
      f16x8 bf = *(const f16x8*)&Bs[(ct*16 + l15)*128 + ((kt*4 + quad) ^ l15)*8];
      acc0 = MFMA_16x16x32(af[0][kt], bf, acc0);
      acc1 = MFMA_16x16x32(af[1][kt], bf, acc1);
    }
    int col = nb*128 + ct*16 + l15;
    int cc = col & 127;
    int hh = cc >> 5, d = cc & 31;
    if (nb == 3) {
      float bgv = bg[cc];
#pragma unroll
      for (int mt = 0; mt < 2; ++mt) {
        f32x4 a = mt ? acc1 : acc0;
#pragma unroll
        for (int r = 0; r < 4; ++r) {
          int jj = j0 + mt*16 + quad*4 + r;
          float sg = 1.0f/(1.0f + __expf(-(a[r] + bgv)));
          gb[(size_t)(i*NSEQ + jj)*CIN + cc] = (f16)sg;
        }
      }
    } else {
      f16* dstb = nb==0 ? qb : (nb==1 ? kb : vb);
      float scale = nb==0 ? 0.17677669529663687f : 1.0f;
#pragma unroll
      for (int mt = 0; mt < 2; ++mt) {
        f32x4 a = mt ? acc1 : acc0;
#pragma unroll
        for (int r = 0; r < 4; ++r) {
          int jj = j0 + mt*16 + quad*4 + r;
          dstb[((size_t)(i*NH + hh)*NSEQ + jj)*DHD + d] = (f16)(a[r]*scale);
        }
      }
    }
  }
}

// ---------------- attention: one block per (i, h). S^T = K.Q^T + bias (MFMA C-init),
// no-max softmax (scores are tiny), P stays in registers as A-operand for P.V.
__global__ __launch_bounds__(256) void k_attn(const f16* __restrict__ qg, const f16* __restrict__ kg,
    const f16* __restrict__ vg, const f16* __restrict__ biasT, f16* __restrict__ og) {
  int b = blockIdx.x; int h = b & 3; int i = b >> 2;
  int t = threadIdx.x; int wave = t >> 6; int lane = t & 63;
  int l15 = lane & 15, quad = lane >> 4;
  __shared__ __align__(16) f16 Ks[NSEQ*40];  // stride 40 f16 = 80 B (2-way max)
  __shared__ __align__(16) f16 Vs[NSEQ*36];  // stride 36 f16 = 72 B (conflict-free u16 reads)
  size_t base = (size_t)(i*NH + h) * NSEQ * DHD;
  for (int p = 0; p < 6; ++p) {
    int c = p*256 + t; int row = c >> 2, ci = c & 3;
    *(f16x8*)&Ks[row*40 + ci*8] = *(const f16x8*)&kg[base + row*DHD + ci*8];
  }
  for (int p = 0; p < 12; ++p) {
    int c = p*256 + t; int row = c >> 3, ci = c & 7;
    *(f16x4*)&Vs[row*36 + ci*4] = *(const f16x4*)&vg[base + row*DHD + ci*4];
  }
  int qt0 = wave*6;
  f16x8 qf[6];
#pragma unroll
  for (int s = 0; s < 6; ++s)
    qf[s] = *(const f16x8*)&qg[base + (size_t)((qt0+s)*16 + l15)*DHD + quad*8];
  f32x4 oa[6][2];
  float lsum[6];
#pragma unroll
  for (int s = 0; s < 6; ++s) { lsum[s] = 0.f; oa[s][0] = (f32x4){0,0,0,0}; oa[s][1] = (f32x4){0,0,0,0}; }
  __syncthreads();
  const f16* bb = biasT + (size_t)h*NSEQ*NSEQ;
  for (int kt = 0; kt < 24; ++kt) {
    f16x8 kf = *(const f16x8*)&Ks[(kt*16 + l15)*40 + quad*8];
    int vbase = (kt*16 + quad*4)*36 + l15;
    f16x4 vf0, vf1;
#pragma unroll
    for (int jj = 0; jj < 4; ++jj) { vf0[jj] = Vs[vbase + jj*36]; vf1[jj] = Vs[vbase + jj*36 + 16]; }
    const f16* bp = bb + (size_t)(kt*16 + quad*4)*NSEQ + l15;
    f32x4 cb[6];
#pragma unroll
    for (int s = 0; s < 6; ++s) {
      int qc = (qt0 + s)*16;
      cb[s][0] = (float)bp[qc];
      cb[s][1] = (float)bp[qc + NSEQ];
      cb[s][2] = (float)bp[qc + 2*NSEQ];
      cb[s][3] = (float)bp[qc + 3*NSEQ];
    }
#pragma unroll
    for (int s = 0; s < 6; ++s) {
      f32x4 st = MFMA_16x16x32(kf, qf[s], cb[s]);   // S^T tile: row=k, col=q, bias pre-added via C
      float p0 = __expf(st[0]), p1 = __expf(st[1]), p2 = __expf(st[2]), p3 = __expf(st[3]);
      lsum[s] += (p0 + p1) + (p2 + p3);
      f16x4 pa; pa[0]=(f16)p0; pa[1]=(f16)p1; pa[2]=(f16)p2; pa[3]=(f16)p3;
      oa[s][0] = MFMA_16x16x16(pa, vf0, oa[s][0]);  // C-layout of S^T == A-layout for K=16 MFMA
      oa[s][1] = MFMA_16x16x16(pa, vf1, oa[s][1]);
    }
  }
#pragma unroll
  for (int s = 0; s < 6; ++s) {
    float lf = lsum[s];
    lf += __shfl_xor(lf, 16);
    lf += __shfl_xor(lf, 32);
    float inv = 1.0f / lf;   // valid for q = l15
#pragma unroll
    for (int r = 0; r < 4; ++r) {
      float invr = __shfl(inv, quad*4 + r);
      int qrow = (qt0+s)*16 + quad*4 + r;
      size_t ob = (size_t)(i*NSEQ + qrow)*(NH*DHD) + h*DHD;
      og[ob + l15]      = (f16)(oa[s][0][r] * invr);
      og[ob + 16 + l15] = (f16)(oa[s][1][r] * invr);
    }
  }
}

// ---------------- final: out = (g*o) @ Wo + bo  (fp32 out)
__global__ __launch_bounds__(256) void k_final(const f16* __restrict__ gb, const f16* __restrict__ ob,
    const f16* __restrict__ WoT, const float* __restrict__ bo, float* __restrict__ out) {
  int mb = blockIdx.x;
  int t = threadIdx.x, wave = t >> 6, lane = t & 63;
  int l15 = lane & 15, quad = lane >> 4;
  __shared__ __align__(16) f16 As[128*128];
  __shared__ __align__(16) f16 Bs[128*128];
  int Mbase = mb*128;
  for (int p = 0; p < 8; ++p) {
    int c = p*256 + t; int row = c >> 4, ci = c & 15;
    int sw = (ci ^ (row & 15)) * 8;
    f16x8 gv = *(const f16x8*)&gb[(size_t)(Mbase + row)*CIN + ci*8];
    f16x8 ov = *(const f16x8*)&ob[(size_t)(Mbase + row)*CIN + ci*8];
    *(f16x8*)&As[row*128 + sw] = gv*ov;
    *(f16x8*)&Bs[row*128 + sw] = *(const f16x8*)&WoT[row*CIN + ci*8];
  }
  __syncthreads();
  int m0 = wave*32;
  f16x8 af[2][4];
#pragma unroll
  for (int mt = 0; mt < 2; ++mt)
#pragma unroll
    for (int kt = 0; kt < 4; ++kt)
      af[mt][kt] = *(const f16x8*)&As[(m0 + mt*16 + l15)*128 + ((kt*4 + quad) ^ l15)*8];
#pragma unroll
  for (int ct = 0; ct < 8; ++ct) {
    f32x4 acc0 = (f32x4){0,0,0,0}, acc1 = (f32x4){0,0,0,0};
#pragma unroll
    for (int kt = 0; kt < 4; ++kt) {
      f16x8 bf = *(const f16x8*)&Bs[(ct*16 + l15)*128 + ((kt*4 + quad) ^ l15)*8];
      acc0 = MFMA_16x16x32(af[0][kt], bf, acc0);
      acc1 = MFMA_16x16x32(af[1][kt], bf, acc1);
    }
    float bov = bo[ct*16 + l15];
#pragma unroll
    for (int mt = 0; mt < 2; ++mt) {
      f32x4 a = mt ? acc1 : acc0;
#pragma unroll
      for (int r = 0; r < 4; ++r) {
        int mrow = Mbase + m0 + mt*16 + quad*4 + r;
        out[(size_t)mrow*CIN + ct*16 + l15] = a[r] + bov;
      }
    }
  }
}

extern "C" void kernel_launch(void* const* d_in, const int* in_sizes, int n_in,
                              void* d_out, int out_size, void* d_ws, size_t ws_size,
                              hipStream_t stream) {
  (void)in_sizes; (void)n_in; (void)out_size; (void)ws_size;
  const float* x    = (const float*)d_in[0];
  const float* sinp = (const float*)d_in[1];
  const float* gam  = (const float*)d_in[2];
  const float* bet  = (const float*)d_in[3];
  const float* Wq1  = (const float*)d_in[4];
  const float* Wq2  = (const float*)d_in[5];
  const float* Wq3  = (const float*)d_in[6];
  const float* Wk1  = (const float*)d_in[7];
  const float* Wk2  = (const float*)d_in[8];
  const float* Wk3  = (const float*)d_in[9];
  const float* Wqa  = (const float*)d_in[10];
  const float* Wka  = (const float*)d_in[11];
  const float* Wva  = (const float*)d_in[12];
  const float* Wg   = (const float*)d_in[13];
  const float* bg   = (const float*)d_in[14];
  const float* Wo   = (const float*)d_in[15];
  const float* bo   = (const float*)d_in[16];
  float* out = (float*)d_out;

  char* w = (char*)d_ws;
  auto carve = [&](size_t bytes) { char* p = w; w += (bytes + 255) & ~(size_t)255; return p; };
  f16*   xn    = (f16*)carve((size_t)NN*CIN*2);    // reused as o after k_proj
  f16*   qb    = (f16*)carve((size_t)NN*CIN*2);
  f16*   kb    = (f16*)carve((size_t)NN*CIN*2);
  f16*   vb    = (f16*)carve((size_t)NN*CIN*2);
  f16*   gbuf  = (f16*)carve((size_t)NN*CIN*2);
  f16*   biasT = (f16*)carve((size_t)NH*NSEQ*NSEQ*2);
  float* rowm  = (float*)carve((size_t)NSEQ*CIN*4);
  float* colm  = (float*)carve((size_t)NSEQ*CIN*4);
  float* qbT   = (float*)carve((size_t)(NH*RNK)*NSEQ*4);
  float* kbT   = (float*)carve((size_t)(NH*RNK)*NSEQ*4);
  f16*   W4T   = (f16*)carve((size_t)512*CIN*2);
  f16*   WoT   = (f16*)carve((size_t)CIN*CIN*2);
  f16*   wmlp  = (f16*)carve((size_t)WMLP_TOT*2);
  f16*   obuf  = xn;

  k_convert<<<320, 256, 0, stream>>>(Wqa, Wka, Wva, Wg, Wo, W4T, WoT);
  k_convert2<<<WMLP_TOT/256, 256, 0, stream>>>(Wq1, Wq2, Wq3, Wk1, Wk2, Wk3, wmlp);
  k_ln<<<NSEQ, 256, 0, stream>>>(x, gam, bet, xn, rowm);
  k_colmean<<<NSEQ, 256, 0, stream>>>(xn, colm);
  k_mlp2<<<24, 256, 0, stream>>>(rowm, colm, sinp, wmlp, qbT, kbT);
  k_bias<<<NH*NSEQ, 128, 0, stream>>>(qbT, kbT, biasT);
  k_proj<<<4608, 256, 0, stream>>>(xn, W4T, bg, qb, kb, vb, gbuf);
  k_attn<<<NH*NSEQ, 256, 0, stream>>>(qb, kb, vb, biasT, obuf);
  k_final<<<1152, 256, 0, stream>>>(gbuf, obuf, WoT, bo, out);
}

// Round 3
// 458.517 us; speedup vs baseline: 1.2033x; 1.1393x over previous
//
#include <hip/hip_runtime.h>
#include <cstdint>
#include <cstddef>

typedef _Float16 f16;
typedef __attribute__((ext_vector_type(2))) _Float16 f16x2;
typedef __attribute__((ext_vector_type(4))) _Float16 f16x4;
typedef __attribute__((ext_vector_type(8))) _Float16 f16x8;
typedef __attribute__((ext_vector_type(4))) float f32x4;

#define MFMA_16x16x32(a,b,c) __builtin_amdgcn_mfma_f32_16x16x32_f16((a),(b),(c),0,0,0)
#define MFMA_16x16x16(a,b,c) __builtin_amdgcn_mfma_f32_16x16x16f16((a),(b),(c),0,0,0)

#define NSEQ 384
#define CIN 128
#define NH 4
#define DHD 32
#define RNK 96
#define SDIM 449
#define MHID 256
#define NN (NSEQ*NSEQ)

#define KPAD 608            // 577 padded to 19*32
#define ZSTR 616            // LDS stride for z (2-way bank aliasing only)
#define HSTR 264            // LDS stride for h1/h2
// f16 transposed-weight pool offsets (elements)
#define OFF_W1 0
#define SZ_W1 (MHID*KPAD)          // 155648 per matrix
#define OFF_W2 (2*SZ_W1)           // 311296
#define SZ_W2 (MHID*MHID)          // 65536
#define OFF_W3 (OFF_W2 + 2*SZ_W2)  // 442368
#define SZ_W3 ((NH*RNK)*MHID)      // 98304
#define WMLP_TOT (OFF_W3 + 2*SZ_W3) // 638976

// ---------------- weight conversion: W4T[col][k] = W*[k][col&127] (f16), WoT[c][hd] = Wo[hd][c]
__global__ __launch_bounds__(256) void k_convert(const float* __restrict__ Wq, const float* __restrict__ Wk,
    const float* __restrict__ Wv, const float* __restrict__ Wg, const float* __restrict__ Wo,
    f16* __restrict__ W4T, f16* __restrict__ WoT) {
  int idx = blockIdx.x*256 + threadIdx.x;   // 0..81919 (640*128)
  int c = idx >> 7, kk = idx & 127;
  if (c < 512) {
    int mat = c >> 7, cc = c & 127;
    const float* src = mat==0 ? Wq : (mat==1 ? Wk : (mat==2 ? Wv : Wg));
    W4T[c*CIN + kk] = (f16)src[kk*CIN + cc];
  } else {
    int cc = c - 512;
    WoT[cc*CIN + kk] = (f16)Wo[kk*CIN + cc];
  }
}

// ---------------- MLP weight transpose+cast into one f16 pool (coalesced writes)
__global__ __launch_bounds__(256) void k_convert2(const float* __restrict__ Wq1, const float* __restrict__ Wq2,
    const float* __restrict__ Wq3, const float* __restrict__ Wk1, const float* __restrict__ Wk2,
    const float* __restrict__ Wk3, f16* __restrict__ wmlp) {
  int idx = blockIdx.x*256 + threadIdx.x;   // 0..638975
  float val;
  if (idx < OFF_W2) {
    int m = idx / SZ_W1, r = idx - m*SZ_W1;
    int c = r / KPAD, kk = r - c*KPAD;
    const float* src = m ? Wk1 : Wq1;
    val = (kk < SDIM + CIN) ? src[kk*MHID + c] : 0.f;
  } else if (idx < OFF_W3) {
    int r = idx - OFF_W2;
    int m = r >> 16, rr = r & 65535;
    int c = rr >> 8, kk = rr & 255;
    const float* src = m ? Wk2 : Wq2;
    val = src[kk*MHID + c];
  } else {
    int r = idx - OFF_W3;
    int m = r / SZ_W3, rr = r - m*SZ_W3;
    int c = rr >> 8, kk = rr & 255;
    const float* src = m ? Wk3 : Wq3;
    val = src[kk*(NH*RNK) + c];
  }
  wmlp[idx] = (f16)val;
}

// ---------------- layernorm + row-mean contribution. 4 blocks per row i; wave handles 2 rows/iter
// (lanes 0-31 -> j, 32-63 -> j+1), float4 loads, 32-lane shuffle reduce, f16x4 stores.
__global__ __launch_bounds__(256) void k_ln(const float* __restrict__ x, const float* __restrict__ gamma,
    const float* __restrict__ beta, f16* __restrict__ xn, float* __restrict__ rowm) {
  int b = blockIdx.x;
  int i = b >> 2, jbase = (b & 3) * 96;
  int t = threadIdx.x, wave = t >> 6, lane = t & 63;
  int half = lane >> 5, l31 = lane & 31;
  int c0 = l31 * 4;
  __shared__ float racc[CIN];
  if (t < CIN) racc[t] = 0.f;
  float4 g4 = *(const float4*)&gamma[c0];
  float4 b4 = *(const float4*)&beta[c0];
  float a0=0,a1=0,a2=0,a3=0;
  __syncthreads();
  for (int it = 0; it < 12; ++it) {
    int j = jbase + it*8 + wave*2 + half;
    const float4 v = *(const float4*)&x[(size_t)(i*NSEQ + j)*CIN + c0];
    float s = (v.x+v.y)+(v.z+v.w);
    float ss = (v.x*v.x+v.y*v.y)+(v.z*v.z+v.w*v.w);
#pragma unroll
    for (int off = 16; off >= 1; off >>= 1) { s += __shfl_xor(s, off); ss += __shfl_xor(ss, off); }
    float mean = s * (1.0f/CIN);
    float var = ss * (1.0f/CIN) - mean*mean;
    float rs = rsqrtf(var + 1e-5f);
    float y0 = (v.x-mean)*rs*g4.x + b4.x;
    float y1 = (v.y-mean)*rs*g4.y + b4.y;
    float y2 = (v.z-mean)*rs*g4.z + b4.z;
    float y3 = (v.w-mean)*rs*g4.w + b4.w;
    f16x4 w; w[0]=(f16)y0; w[1]=(f16)y1; w[2]=(f16)y2; w[3]=(f16)y3;
    *(f16x4*)&xn[(size_t)(i*NSEQ + j)*CIN + c0] = w;
    a0+=y0; a1+=y1; a2+=y2; a3+=y3;
  }
  atomicAdd(&racc[c0], a0); atomicAdd(&racc[c0+1], a1);
  atomicAdd(&racc[c0+2], a2); atomicAdd(&racc[c0+3], a3);
  __syncthreads();
  if (t < CIN) atomicAdd(&rowm[i*CIN + t], racc[t] * (1.0f/NSEQ));
}

// ---------------- column means (mean over axis 0) from f16 xn
__global__ __launch_bounds__(256) void k_colmean(const f16* __restrict__ xn, float* __restrict__ colm) {
  int j = blockIdx.x; int t = threadIdx.x;
  int c = t & 127, half = t >> 7;
  float acc = 0.f;
  int i0 = half*192;
#pragma unroll 4
  for (int ii = i0; ii < i0 + 192; ++ii)
    acc += (float)xn[(size_t)(ii*NSEQ + j)*CIN + c];
  __shared__ float sb[256];
  sb[t] = acc;
  __syncthreads();
  if (t < 128) colm[j*CIN + t] = (sb[t] + sb[t+128]) * (1.0f/NSEQ);
}

// ---------------- fused bias MLP (MFMA): 32 rows/block, 3 layers block-local.
// writes transposed qbT/kbT[o][row] fp32, o = h*96+r
__global__ __launch_bounds__(256) void k_mlp2(const float* __restrict__ rowm, const float* __restrict__ colm,
    const float* __restrict__ sinp, const f16* __restrict__ wmlp,
    float* __restrict__ qbT, float* __restrict__ kbT) {
  int b = blockIdx.x;
  bool isQ = b < 12;
  int r0 = (isQ ? b : b - 12) * 32;
  const float* mean = isQ ? rowm : colm;
  const f16* W1T = wmlp + (isQ ? 0 : SZ_W1);
  const f16* W2T = wmlp + OFF_W2 + (isQ ? 0 : SZ_W2);
  const f16* W3T = wmlp + OFF_W3 + (isQ ? 0 : SZ_W3);
  float* outp = isQ ? qbT : kbT;
  int t = threadIdx.x, wave = t >> 6, lane = t & 63;
  int l15 = lane & 15, quad = lane >> 4;
  int rt = wave & 1, ch = wave >> 1;   // row-tile, col-half

  __shared__ __align__(16) f16 z[32*ZSTR];
  __shared__ __align__(16) f16 hbuf[2][32*HSTR];

  for (int idx = t; idx < 32*KPAD; idx += 256) {
    int row = idx / KPAD, u = idx - row*KPAD;
    float v;
    if (u < CIN) v = mean[(r0+row)*CIN + u];
    else if (u < CIN + SDIM) v = sinp[(r0+row)*SDIM + (u - CIN)];
    else v = 0.f;
    z[row*ZSTR + u] = (f16)v;
  }
  __syncthreads();

  // ---- layer 1: [32 x 608] @ W1T^T -> tanh -> h1 [32 x 256]
  {
    f32x4 acc[8];
#pragma unroll
    for (int c = 0; c < 8; ++c) acc[c] = (f32x4){0,0,0,0};
    for (int ks = 0; ks < 19; ++ks) {
      f16x8 af = *(const f16x8*)&z[(rt*16 + l15)*ZSTR + ks*32 + quad*8];
#pragma unroll
      for (int c = 0; c < 8; ++c) {
        f16x8 bf = *(const f16x8*)&W1T[(size_t)((ch*8 + c)*16 + l15)*KPAD + ks*32 + quad*8];
        acc[c] = MFMA_16x16x32(af, bf, acc[c]);
      }
    }
#pragma unroll
    for (int c = 0; c < 8; ++c) {
      int col = (ch*8 + c)*16 + l15;
#pragma unroll
      for (int r = 0; r < 4; ++r) {
        float th = 1.f - 2.f/(1.f + __expf(2.f*acc[c][r]));
        hbuf[0][(rt*16 + quad*4 + r)*HSTR + col] = (f16)th;
      }
    }
  }
  __syncthreads();

  // ---- layer 2: h1 @ W2T^T -> tanh -> h2 [32 x 256]
  {
    f32x4 acc[8];
#pragma unroll
    for (int c = 0; c < 8; ++c) acc[c] = (f32x4){0,0,0,0};
    for (int ks = 0; ks < 8; ++ks) {
      f16x8 af = *(const f16x8*)&hbuf[0][(rt*16 + l15)*HSTR + ks*32 + quad*8];
#pragma unroll
      for (int c = 0; c < 8; ++c) {
        f16x8 bf = *(const f16x8*)&W2T[(size_t)((ch*8 + c)*16 + l15)*MHID + ks*32 + quad*8];
        acc[c] = MFMA_16x16x32(af, bf, acc[c]);
      }
    }
#pragma unroll
    for (int c = 0; c < 8; ++c) {
      int col = (ch*8 + c)*16 + l15;
#pragma unroll
      for (int r = 0; r < 4; ++r) {
        float th = 1.f - 2.f/(1.f + __expf(2.f*acc[c][r]));
        hbuf[1][(rt*16 + quad*4 + r)*HSTR + col] = (f16)th;
      }
    }
  }
  __syncthreads();

  // ---- layer 3: h2 @ W3T^T -> [32 x 384] -> transposed fp32 store
  {
    f32x4 acc[12];
#pragma unroll
    for (int c = 0; c < 12; ++c) acc[c] = (f32x4){0,0,0,0};
    for (int ks = 0; ks < 8; ++ks) {
      f16x8 af = *(const f16x8*)&hbuf[1][(rt*16 + l15)*HSTR + ks*32 + quad*8];
#pragma unroll
      for (int c = 0; c < 12; ++c) {
        f16x8 bf = *(const f16x8*)&W3T[(size_t)((ch*12 + c)*16 + l15)*MHID + ks*32 + quad*8];
        acc[c] = MFMA_16x16x32(af, bf, acc[c]);
      }
    }
#pragma unroll
    for (int c = 0; c < 12; ++c) {
      int o = (ch*12 + c)*16 + l15;
#pragma unroll
      for (int r = 0; r < 4; ++r)
        outp[o*NSEQ + r0 + rt*16 + quad*4 + r] = acc[c][r];
    }
  }
}

// ---------------- low-rank bias outer product into MFMA C-fragment layout (fp32):
// bias4[h][k>>2][q][k&3]; block = (h, kgroup), 128 threads x 3 q each.
__global__ __launch_bounds__(128) void k_bias(const float* __restrict__ qbT, const float* __restrict__ kbT,
    float* __restrict__ bias4) {
  int b = blockIdx.x;            // h*96 + kg
  int h = b / 96, kg = b - h*96;
  int t = threadIdx.x;
  __shared__ float4 kr[RNK];
  if (t < RNK) kr[t] = *(const float4*)&kbT[(size_t)(h*RNK + t)*NSEQ + kg*4];
  __syncthreads();
  float acc[3][4];
#pragma unroll
  for (int m = 0; m < 3; ++m)
#pragma unroll
    for (int r = 0; r < 4; ++r) acc[m][r] = 0.f;
  for (int r = 0; r < RNK; ++r) {
    float4 kv = kr[r];
    const float* qrow = qbT + (size_t)(h*RNK + r)*NSEQ;
    float q0 = qrow[t], q1 = qrow[t+128], q2 = qrow[t+256];
    acc[0][0]+=q0*kv.x; acc[0][1]+=q0*kv.y; acc[0][2]+=q0*kv.z; acc[0][3]+=q0*kv.w;
    acc[1][0]+=q1*kv.x; acc[1][1]+=q1*kv.y; acc[1][2]+=q1*kv.z; acc[1][3]+=q1*kv.w;
    acc[2][0]+=q2*kv.x; acc[2][1]+=q2*kv.y; acc[2][2]+=q2*kv.z; acc[2][3]+=q2*kv.w;
  }
#pragma unroll
  for (int m = 0; m < 3; ++m) {
    int q = t + m*128;
    f32x4 w; w[0]=acc[m][0]; w[1]=acc[m][1]; w[2]=acc[m][2]; w[3]=acc[m][3];
    *(f32x4*)&bias4[((size_t)b*NSEQ + q)*4] = w;
  }
}

// ---------------- projections: xn @ [Wq|Wk|Wv|Wg] -> q,k,v ([i,h,n,d] f16, q scaled), g ([i*N+j, hd])
__global__ __launch_bounds__(256) void k_proj(const f16* __restrict__ xn, const f16* __restrict__ W4T,
    const float* __restrict__ bg, f16* __restrict__ qb, f16* __restrict__ kb, f16* __restrict__ vb,
    f16* __restrict__ gb) {
  int b = blockIdx.x; int mb = b >> 2, nb = b & 3;
  int t = threadIdx.x, wave = t >> 6, lane = t & 63;
  int l15 = lane & 15, quad = lane >> 4;
  __shared__ __align__(16) f16 As[128*128];  // XOR-swizzled chunks of 8 f16
  __shared__ __align__(16) f16 Bs[128*128];
  int Mbase = mb*128;
  for (int p = 0; p < 8; ++p) {
    int c = p*256 + t; int row = c >> 4, ci = c & 15;
    int sw = (ci ^ (row & 15)) * 8;
    *(f16x8*)&As[row*128 + sw] = *(const f16x8*)&xn[(size_t)(Mbase + row)*CIN + ci*8];
    *(f16x8*)&Bs[row*128 + sw] = *(const f16x8*)&W4T[(size_t)(nb*128 + row)*CIN + ci*8];
  }
  __syncthreads();
  int m0 = wave*32;
  f16x8 af[2][4];
#pragma unroll
  for (int mt = 0; mt < 2; ++mt)
#pragma unroll
    for (int kt = 0; kt < 4; ++kt)
      af[mt][kt] = *(const f16x8*)&As[(m0 + mt*16 + l15)*128 + ((kt*4 + quad) ^ l15)*8];
  int i = mb/3, j0 = (mb - (mb/3)*3)*128 + m0;
#pragma unroll
  for (int ct = 0; ct < 8; ++ct) {
    f32x4 acc0 = (f32x4){0,0,0,0}, acc1 = (f32x4){0,0,0,0};
#pragma unroll
    for (int kt = 0; kt < 4; ++kt) {
      f16x8 bf = *(const f16x8*)&Bs[(ct*16 + l15)*128 + ((kt*4 + quad) ^ l15)*8];
      acc0 = MFMA_16x16x32(af[0][kt], bf, acc0);
      acc1 = MFMA_16x16x32(af[1][kt], bf, acc1);
    }
    int col = nb*128 + ct*16 + l15;
    int cc = col & 127;
    int hh = cc >> 5, d = cc & 31;
    if (nb == 3) {
      float bgv = bg[cc];
#pragma unroll
      for (int mt = 0; mt < 2; ++mt) {
        f32x4 a = mt ? acc1 : acc0;
#pragma unroll
        for (int r = 0; r < 4; ++r) {
          int jj = j0 + mt*16 + quad*4 + r;
          float sg = 1.0f/(1.0f + __expf(-(a[r] + bgv)));
          gb[(size_t)(i*NSEQ + jj)*CIN + cc] = (f16)sg;
        }
      }
    } else {
      f16* dstb = nb==0 ? qb : (nb==1 ? kb : vb);
      float scale = nb==0 ? 0.17677669529663687f : 1.0f;
#pragma unroll
      for (int mt = 0; mt < 2; ++mt) {
        f32x4 a = mt ? acc1 : acc0;
#pragma unroll
        for (int r = 0; r < 4; ++r) {
          int jj = j0 + mt*16 + quad*4 + r;
          dstb[((size_t)(i*NH + hh)*NSEQ + jj)*DHD + d] = (f16)(a[r]*scale);
        }
      }
    }
  }
}

// ---------------- attention: one block per (i, h). S^T = K.Q^T + bias (MFMA C-init from
// fragment-layout fp32 bias4 -> one f32x4 load per (s,kt)), no-max softmax, P in registers.
__global__ __launch_bounds__(256) void k_attn(const f16* __restrict__ qg, const f16* __restrict__ kg,
    const f16* __restrict__ vg, const float* __restrict__ bias4, f16* __restrict__ og) {
  int b = blockIdx.x; int h = b & 3; int i = b >> 2;
  int t = threadIdx.x; int wave = t >> 6; int lane = t & 63;
  int l15 = lane & 15, quad = lane >> 4;
  __shared__ __align__(16) f16 Ks[NSEQ*40];  // stride 40 f16 = 80 B (2-way max)
  __shared__ __align__(16) f16 Vs[NSEQ*36];  // stride 36 f16 = 72 B (conflict-free u16 reads)
  size_t base = (size_t)(i*NH + h) * NSEQ * DHD;
  for (int p = 0; p < 6; ++p) {
    int c = p*256 + t; int row = c >> 2, ci = c & 3;
    *(f16x8*)&Ks[row*40 + ci*8] = *(const f16x8*)&kg[base + row*DHD + ci*8];
  }
  for (int p = 0; p < 12; ++p) {
    int c = p*256 + t; int row = c >> 3, ci = c & 7;
    *(f16x4*)&Vs[row*36 + ci*4] = *(const f16x4*)&vg[base + row*DHD + ci*4];
  }
  int qt0 = wave*6;
  f16x8 qf[6];
#pragma unroll
  for (int s = 0; s < 6; ++s)
    qf[s] = *(const f16x8*)&qg[base + (size_t)((qt0+s)*16 + l15)*DHD + quad*8];
  f32x4 oa[6][2];
  float lsum[6];
#pragma unroll
  for (int s = 0; s < 6; ++s) { lsum[s] = 0.f; oa[s][0] = (f32x4){0,0,0,0}; oa[s][1] = (f32x4){0,0,0,0}; }
  __syncthreads();
  for (int kt = 0; kt < 24; ++kt) {
    f16x8 kf = *(const f16x8*)&Ks[(kt*16 + l15)*40 + quad*8];
    int vbase = (kt*16 + quad*4)*36 + l15;
    f16x4 vf0, vf1;
#pragma unroll
    for (int jj = 0; jj < 4; ++jj) { vf0[jj] = Vs[vbase + jj*36]; vf1[jj] = Vs[vbase + jj*36 + 16]; }
    const float* bp = bias4 + (((size_t)h*96 + kt*4 + quad)*NSEQ + qt0*16 + l15)*4;
    f32x4 cb[6];
#pragma unroll
    for (int s = 0; s < 6; ++s) cb[s] = *(const f32x4*)(bp + s*64);
#pragma unroll
    for (int s = 0; s < 6; ++s) {
      f32x4 st = MFMA_16x16x32(kf, qf[s], cb[s]);   // S^T tile: row=k, col=q, bias pre-added via C
      float p0 = __expf(st[0]), p1 = __expf(st[1]), p2 = __expf(st[2]), p3 = __expf(st[3]);
      lsum[s] += (p0 + p1) + (p2 + p3);
      f16x4 pa; pa[0]=(f16)p0; pa[1]=(f16)p1; pa[2]=(f16)p2; pa[3]=(f16)p3;
      oa[s][0] = MFMA_16x16x16(pa, vf0, oa[s][0]);  // C-layout of S^T == A-layout for K=16 MFMA
      oa[s][1] = MFMA_16x16x16(pa, vf1, oa[s][1]);
    }
  }
#pragma unroll
  for (int s = 0; s < 6; ++s) {
    float lf = lsum[s];
    lf += __shfl_xor(lf, 16);
    lf += __shfl_xor(lf, 32);
    float inv = 1.0f / lf;   // valid for q = l15
#pragma unroll
    for (int r = 0; r < 4; ++r) {
      float invr = __shfl(inv, quad*4 + r);
      int qrow = (qt0+s)*16 + quad*4 + r;
      size_t ob = (size_t)(i*NSEQ + qrow)*(NH*DHD) + h*DHD;
      og[ob + l15]      = (f16)(oa[s][0][r] * invr);
      og[ob + 16 + l15] = (f16)(oa[s][1][r] * invr);
    }
  }
}

// ---------------- final: out = (g*o) @ Wo + bo  (fp32 out)
__global__ __launch_bounds__(256) void k_final(const f16* __restrict__ gb, const f16* __restrict__ ob,
    const f16* __restrict__ WoT, const float* __restrict__ bo, float* __restrict__ out) {
  int mb = blockIdx.x;
  int t = threadIdx.x, wave = t >> 6, lane = t & 63;
  int l15 = lane & 15, quad = lane >> 4;
  __shared__ __align__(16) f16 As[128*128];
  __shared__ __align__(16) f16 Bs[128*128];
  int Mbase = mb*128;
  for (int p = 0; p < 8; ++p) {
    int c = p*256 + t; int row = c >> 4, ci = c & 15;
    int sw = (ci ^ (row & 15)) * 8;
    f16x8 gv = *(const f16x8*)&gb[(size_t)(Mbase + row)*CIN + ci*8];
    f16x8 ov = *(const f16x8*)&ob[(size_t)(Mbase + row)*CIN + ci*8];
    *(f16x8*)&As[row*128 + sw] = gv*ov;
    *(f16x8*)&Bs[row*128 + sw] = *(const f16x8*)&WoT[row*CIN + ci*8];
  }
  __syncthreads();
  int m0 = wave*32;
  f16x8 af[2][4];
#pragma unroll
  for (int mt = 0; mt < 2; ++mt)
#pragma unroll
    for (int kt = 0; kt < 4; ++kt)
      af[mt][kt] = *(const f16x8*)&As[(m0 + mt*16 + l15)*128 + ((kt*4 + quad) ^ l15)*8];
#pragma unroll
  for (int ct = 0; ct < 8; ++ct) {
    f32x4 acc0 = (f32x4){0,0,0,0}, acc1 = (f32x4){0,0,0,0};
#pragma unroll
    for (int kt = 0; kt < 4; ++kt) {
      f16x8 bf = *(const f16x8*)&Bs[(ct*16 + l15)*128 + ((kt*4 + quad) ^ l15)*8];
      acc0 = MFMA_16x16x32(af[0][kt], bf, acc0);
      acc1 = MFMA_16x16x32(af[1][kt], bf, acc1);
    }
    float bov = bo[ct*16 + l15];
#pragma unroll
    for (int mt = 0; mt < 2; ++mt) {
      f32x4 a = mt ? acc1 : acc0;
#pragma unroll
      for (int r = 0; r < 4; ++r) {
        int mrow = Mbase + m0 + mt*16 + quad*4 + r;
        out[(size_t)mrow*CIN + ct*16 + l15] = a[r] + bov;
      }
    }
  }
}

extern "C" void kernel_launch(void* const* d_in, const int* in_sizes, int n_in,
                              void* d_out, int out_size, void* d_ws, size_t ws_size,
                              hipStream_t stream) {
  (void)in_sizes; (void)n_in; (void)out_size; (void)ws_size;
  const float* x    = (const float*)d_in[0];
  const float* sinp = (const float*)d_in[1];
  const float* gam  = (const float*)d_in[2];
  const float* bet  = (const float*)d_in[3];
  const float* Wq1  = (const float*)d_in[4];
  const float* Wq2  = (const float*)d_in[5];
  const float* Wq3  = (const float*)d_in[6];
  const float* Wk1  = (const float*)d_in[7];
  const float* Wk2  = (const float*)d_in[8];
  const float* Wk3  = (const float*)d_in[9];
  const float* Wqa  = (const float*)d_in[10];
  const float* Wka  = (const float*)d_in[11];
  const float* Wva  = (const float*)d_in[12];
  const float* Wg   = (const float*)d_in[13];
  const float* bg   = (const float*)d_in[14];
  const float* Wo   = (const float*)d_in[15];
  const float* bo   = (const float*)d_in[16];
  float* out = (float*)d_out;

  char* w = (char*)d_ws;
  auto carve = [&](size_t bytes) { char* p = w; w += (bytes + 255) & ~(size_t)255; return p; };
  f16*   xn    = (f16*)carve((size_t)NN*CIN*2);    // reused as o after k_proj
  f16*   qb    = (f16*)carve((size_t)NN*CIN*2);
  f16*   kb    = (f16*)carve((size_t)NN*CIN*2);
  f16*   vb    = (f16*)carve((size_t)NN*CIN*2);
  f16*   gbuf  = (f16*)carve((size_t)NN*CIN*2);
  float* bias4 = (float*)carve((size_t)NH*NSEQ*NSEQ*4);
  float* rowm  = (float*)carve((size_t)NSEQ*CIN*4);
  float* colm  = (float*)carve((size_t)NSEQ*CIN*4);
  float* qbT   = (float*)carve((size_t)(NH*RNK)*NSEQ*4);
  float* kbT   = (float*)carve((size_t)(NH*RNK)*NSEQ*4);
  f16*   W4T   = (f16*)carve((size_t)512*CIN*2);
  f16*   WoT   = (f16*)carve((size_t)CIN*CIN*2);
  f16*   wmlp  = (f16*)carve((size_t)WMLP_TOT*2);
  f16*   obuf  = xn;

  hipMemsetAsync(rowm, 0, (size_t)NSEQ*CIN*4, stream);
  k_convert<<<320, 256, 0, stream>>>(Wqa, Wka, Wva, Wg, Wo, W4T, WoT);
  k_convert2<<<WMLP_TOT/256, 256, 0, stream>>>(Wq1, Wq2, Wq3, Wk1, Wk2, Wk3, wmlp);
  k_ln<<<NSEQ*4, 256, 0, stream>>>(x, gam, bet, xn, rowm);
  k_colmean<<<NSEQ, 256, 0, stream>>>(xn, colm);
  k_mlp2<<<24, 256, 0, stream>>>(rowm, colm, sinp, wmlp, qbT, kbT);
  k_bias<<<NH*96, 128, 0, stream>>>(qbT, kbT, bias4);
  k_proj<<<4608, 256, 0, stream>>>(xn, W4T, bg, qb, kb, vb, gbuf);
  k_attn<<<NH*NSEQ, 256, 0, stream>>>(qb, kb, vb, bias4, obuf);
  k_final<<<1152, 256, 0, stream>>>(gbuf, obuf, WoT, bo, out);
}

// Round 4
// 445.247 us; speedup vs baseline: 1.2392x; 1.0298x over previous
//
#include <hip/hip_runtime.h>
#include <cstdint>
#include <cstddef>

typedef _Float16 f16;
typedef __attribute__((ext_vector_type(2))) _Float16 f16x2;
typedef __attribute__((ext_vector_type(4))) _Float16 f16x4;
typedef __attribute__((ext_vector_type(8))) _Float16 f16x8;
typedef __attribute__((ext_vector_type(4))) float f32x4;

#define MFMA_16x16x32(a,b,c) __builtin_amdgcn_mfma_f32_16x16x32_f16((a),(b),(c),0,0,0)
#define MFMA_16x16x16(a,b,c) __builtin_amdgcn_mfma_f32_16x16x16f16((a),(b),(c),0,0,0)

#define NSEQ 384
#define CIN 128
#define NH 4
#define DHD 32
#define RNK 96
#define SDIM 449
#define MHID 256
#define NN (NSEQ*NSEQ)
#define LOG2E 1.4426950408889634f

#define KPAD 608            // 577 padded to 19*32
#define ZSTR 616            // LDS stride for z (2-way bank aliasing only)
#define HSTR 264            // LDS stride for h1/h2
// f16 transposed-weight pool offsets (elements)
#define OFF_W1 0
#define SZ_W1 (MHID*KPAD)          // 155648 per matrix
#define OFF_W2 (2*SZ_W1)           // 311296
#define SZ_W2 (MHID*MHID)          // 65536
#define OFF_W3 (OFF_W2 + 2*SZ_W2)  // 442368
#define SZ_W3 ((NH*RNK)*MHID)      // 98304
#define WMLP_TOT (OFF_W3 + 2*SZ_W3) // 638976

// ---------------- weight conversion: W4T[col][k] = W*[k][col&127] (f16), WoT[c][hd] = Wo[hd][c]
__global__ __launch_bounds__(256) void k_convert(const float* __restrict__ Wq, const float* __restrict__ Wk,
    const float* __restrict__ Wv, const float* __restrict__ Wg, const float* __restrict__ Wo,
    f16* __restrict__ W4T, f16* __restrict__ WoT) {
  int idx = blockIdx.x*256 + threadIdx.x;   // 0..81919 (640*128)
  int c = idx >> 7, kk = idx & 127;
  if (c < 512) {
    int mat = c >> 7, cc = c & 127;
    const float* src = mat==0 ? Wq : (mat==1 ? Wk : (mat==2 ? Wv : Wg));
    W4T[c*CIN + kk] = (f16)src[kk*CIN + cc];
  } else {
    int cc = c - 512;
    WoT[cc*CIN + kk] = (f16)Wo[kk*CIN + cc];
  }
}

// ---------------- MLP weight transpose+cast into one f16 pool (coalesced writes)
__global__ __launch_bounds__(256) void k_convert2(const float* __restrict__ Wq1, const float* __restrict__ Wq2,
    const float* __restrict__ Wq3, const float* __restrict__ Wk1, const float* __restrict__ Wk2,
    const float* __restrict__ Wk3, f16* __restrict__ wmlp) {
  int idx = blockIdx.x*256 + threadIdx.x;   // 0..638975
  float val;
  if (idx < OFF_W2) {
    int m = idx / SZ_W1, r = idx - m*SZ_W1;
    int c = r / KPAD, kk = r - c*KPAD;
    const float* src = m ? Wk1 : Wq1;
    val = (kk < SDIM + CIN) ? src[kk*MHID + c] : 0.f;
  } else if (idx < OFF_W3) {
    int r = idx - OFF_W2;
    int m = r >> 16, rr = r & 65535;
    int c = rr >> 8, kk = rr & 255;
    const float* src = m ? Wk2 : Wq2;
    val = src[kk*MHID + c];
  } else {
    int r = idx - OFF_W3;
    int m = r / SZ_W3, rr = r - m*SZ_W3;
    int c = rr >> 8, kk = rr & 255;
    const float* src = m ? Wk3 : Wq3;
    val = src[kk*(NH*RNK) + c];
  }
  wmlp[idx] = (f16)val;
}

// ---------------- layernorm + row-mean contribution. 4 blocks per row i; wave handles 2 rows/iter
__global__ __launch_bounds__(256) void k_ln(const float* __restrict__ x, const float* __restrict__ gamma,
    const float* __restrict__ beta, f16* __restrict__ xn, float* __restrict__ rowm) {
  int b = blockIdx.x;
  int i = b >> 2, jbase = (b & 3) * 96;
  int t = threadIdx.x, wave = t >> 6, lane = t & 63;
  int half = lane >> 5, l31 = lane & 31;
  int c0 = l31 * 4;
  __shared__ float racc[CIN];
  if (t < CIN) racc[t] = 0.f;
  float4 g4 = *(const float4*)&gamma[c0];
  float4 b4 = *(const float4*)&beta[c0];
  float a0=0,a1=0,a2=0,a3=0;
  __syncthreads();
  for (int it = 0; it < 12; ++it) {
    int j = jbase + it*8 + wave*2 + half;
    const float4 v = *(const float4*)&x[(size_t)(i*NSEQ + j)*CIN + c0];
    float s = (v.x+v.y)+(v.z+v.w);
    float ss = (v.x*v.x+v.y*v.y)+(v.z*v.z+v.w*v.w);
#pragma unroll
    for (int off = 16; off >= 1; off >>= 1) { s += __shfl_xor(s, off); ss += __shfl_xor(ss, off); }
    float mean = s * (1.0f/CIN);
    float var = ss * (1.0f/CIN) - mean*mean;
    float rs = rsqrtf(var + 1e-5f);
    float y0 = (v.x-mean)*rs*g4.x + b4.x;
    float y1 = (v.y-mean)*rs*g4.y + b4.y;
    float y2 = (v.z-mean)*rs*g4.z + b4.z;
    float y3 = (v.w-mean)*rs*g4.w + b4.w;
    f16x4 w; w[0]=(f16)y0; w[1]=(f16)y1; w[2]=(f16)y2; w[3]=(f16)y3;
    *(f16x4*)&xn[(size_t)(i*NSEQ + j)*CIN + c0] = w;
    a0+=y0; a1+=y1; a2+=y2; a3+=y3;
  }
  atomicAdd(&racc[c0], a0); atomicAdd(&racc[c0+1], a1);
  atomicAdd(&racc[c0+2], a2); atomicAdd(&racc[c0+3], a3);
  __syncthreads();
  if (t < CIN) atomicAdd(&rowm[i*CIN + t], racc[t] * (1.0f/NSEQ));
}

// ---------------- column means (mean over axis 0) from f16 xn
__global__ __launch_bounds__(256) void k_colmean(const f16* __restrict__ xn, float* __restrict__ colm) {
  int j = blockIdx.x; int t = threadIdx.x;
  int c = t & 127, half = t >> 7;
  float acc = 0.f;
  int i0 = half*192;
#pragma unroll 4
  for (int ii = i0; ii < i0 + 192; ++ii)
    acc += (float)xn[(size_t)(ii*NSEQ + j)*CIN + c];
  __shared__ float sb[256];
  sb[t] = acc;
  __syncthreads();
  if (t < 128) colm[j*CIN + t] = (sb[t] + sb[t+128]) * (1.0f/NSEQ);
}

// ---------------- fused bias MLP (MFMA): 32 rows/block, 3 layers block-local.
__global__ __launch_bounds__(256) void k_mlp2(const float* __restrict__ rowm, const float* __restrict__ colm,
    const float* __restrict__ sinp, const f16* __restrict__ wmlp,
    float* __restrict__ qbT, float* __restrict__ kbT) {
  int b = blockIdx.x;
  bool isQ = b < 12;
  int r0 = (isQ ? b : b - 12) * 32;
  const float* mean = isQ ? rowm : colm;
  const f16* W1T = wmlp + (isQ ? 0 : SZ_W1);
  const f16* W2T = wmlp + OFF_W2 + (isQ ? 0 : SZ_W2);
  const f16* W3T = wmlp + OFF_W3 + (isQ ? 0 : SZ_W3);
  float* outp = isQ ? qbT : kbT;
  int t = threadIdx.x, wave = t >> 6, lane = t & 63;
  int l15 = lane & 15, quad = lane >> 4;
  int rt = wave & 1, ch = wave >> 1;   // row-tile, col-half

  __shared__ __align__(16) f16 z[32*ZSTR];
  __shared__ __align__(16) f16 hbuf[2][32*HSTR];

  for (int idx = t; idx < 32*KPAD; idx += 256) {
    int row = idx / KPAD, u = idx - row*KPAD;
    float v;
    if (u < CIN) v = mean[(r0+row)*CIN + u];
    else if (u < CIN + SDIM) v = sinp[(r0+row)*SDIM + (u - CIN)];
    else v = 0.f;
    z[row*ZSTR + u] = (f16)v;
  }
  __syncthreads();

  {
    f32x4 acc[8];
#pragma unroll
    for (int c = 0; c < 8; ++c) acc[c] = (f32x4){0,0,0,0};
    for (int ks = 0; ks < 19; ++ks) {
      f16x8 af = *(const f16x8*)&z[(rt*16 + l15)*ZSTR + ks*32 + quad*8];
#pragma unroll
      for (int c = 0; c < 8; ++c) {
        f16x8 bf = *(const f16x8*)&W1T[(size_t)((ch*8 + c)*16 + l15)*KPAD + ks*32 + quad*8];
        acc[c] = MFMA_16x16x32(af, bf, acc[c]);
      }
    }
#pragma unroll
    for (int c = 0; c < 8; ++c) {
      int col = (ch*8 + c)*16 + l15;
#pragma unroll
      for (int r = 0; r < 4; ++r) {
        float th = 1.f - 2.f/(1.f + __expf(2.f*acc[c][r]));
        hbuf[0][(rt*16 + quad*4 + r)*HSTR + col] = (f16)th;
      }
    }
  }
  __syncthreads();

  {
    f32x4 acc[8];
#pragma unroll
    for (int c = 0; c < 8; ++c) acc[c] = (f32x4){0,0,0,0};
    for (int ks = 0; ks < 8; ++ks) {
      f16x8 af = *(const f16x8*)&hbuf[0][(rt*16 + l15)*HSTR + ks*32 + quad*8];
#pragma unroll
      for (int c = 0; c < 8; ++c) {
        f16x8 bf = *(const f16x8*)&W2T[(size_t)((ch*8 + c)*16 + l15)*MHID + ks*32 + quad*8];
        acc[c] = MFMA_16x16x32(af, bf, acc[c]);
      }
    }
#pragma unroll
    for (int c = 0; c < 8; ++c) {
      int col = (ch*8 + c)*16 + l15;
#pragma unroll
      for (int r = 0; r < 4; ++r) {
        float th = 1.f - 2.f/(1.f + __expf(2.f*acc[c][r]));
        hbuf[1][(rt*16 + quad*4 + r)*HSTR + col] = (f16)th;
      }
    }
  }
  __syncthreads();

  {
    f32x4 acc[12];
#pragma unroll
    for (int c = 0; c < 12; ++c) acc[c] = (f32x4){0,0,0,0};
    for (int ks = 0; ks < 8; ++ks) {
      f16x8 af = *(const f16x8*)&hbuf[1][(rt*16 + l15)*HSTR + ks*32 + quad*8];
#pragma unroll
      for (int c = 0; c < 12; ++c) {
        f16x8 bf = *(const f16x8*)&W3T[(size_t)((ch*12 + c)*16 + l15)*MHID + ks*32 + quad*8];
        acc[c] = MFMA_16x16x32(af, bf, acc[c]);
      }
    }
#pragma unroll
    for (int c = 0; c < 12; ++c) {
      int o = (ch*12 + c)*16 + l15;
#pragma unroll
      for (int r = 0; r < 4; ++r)
        outp[o*NSEQ + r0 + rt*16 + quad*4 + r] = acc[c][r];
    }
  }
}

// ---------------- low-rank bias outer product into MFMA C-fragment layout (fp32, pre-scaled by LOG2E):
// bias4[h][k>>2][q][k&3]; block = (h, kgroup), 128 threads x 3 q each.
__global__ __launch_bounds__(128) void k_bias(const float* __restrict__ qbT, const float* __restrict__ kbT,
    float* __restrict__ bias4) {
  int b = blockIdx.x;            // h*96 + kg
  int h = b / 96, kg = b - h*96;
  int t = threadIdx.x;
  __shared__ float4 kr[RNK];
  if (t < RNK) kr[t] = *(const float4*)&kbT[(size_t)(h*RNK + t)*NSEQ + kg*4];
  __syncthreads();
  float acc[3][4];
#pragma unroll
  for (int m = 0; m < 3; ++m)
#pragma unroll
    for (int r = 0; r < 4; ++r) acc[m][r] = 0.f;
  for (int r = 0; r < RNK; ++r) {
    float4 kv = kr[r];
    const float* qrow = qbT + (size_t)(h*RNK + r)*NSEQ;
    float q0 = qrow[t], q1 = qrow[t+128], q2 = qrow[t+256];
    acc[0][0]+=q0*kv.x; acc[0][1]+=q0*kv.y; acc[0][2]+=q0*kv.z; acc[0][3]+=q0*kv.w;
    acc[1][0]+=q1*kv.x; acc[1][1]+=q1*kv.y; acc[1][2]+=q1*kv.z; acc[1][3]+=q1*kv.w;
    acc[2][0]+=q2*kv.x; acc[2][1]+=q2*kv.y; acc[2][2]+=q2*kv.z; acc[2][3]+=q2*kv.w;
  }
#pragma unroll
  for (int m = 0; m < 3; ++m) {
    int q = t + m*128;
    f32x4 w; w[0]=acc[m][0]*LOG2E; w[1]=acc[m][1]*LOG2E; w[2]=acc[m][2]*LOG2E; w[3]=acc[m][3]*LOG2E;
    *(f32x4*)&bias4[((size_t)b*NSEQ + q)*4] = w;
  }
}

// ---------------- projections: xn @ [Wq|Wk|Wv|Wg] -> q,k,v ([i,h,n,d] f16, q scaled by log2e/sqrt(d)), g
__global__ __launch_bounds__(256) void k_proj(const f16* __restrict__ xn, const f16* __restrict__ W4T,
    const float* __restrict__ bg, f16* __restrict__ qb, f16* __restrict__ kb, f16* __restrict__ vb,
    f16* __restrict__ gb) {
  int b = blockIdx.x; int mb = b >> 2, nb = b & 3;
  int t = threadIdx.x, wave = t >> 6, lane = t & 63;
  int l15 = lane & 15, quad = lane >> 4;
  __shared__ __align__(16) f16 As[128*128];  // XOR-swizzled chunks of 8 f16
  __shared__ __align__(16) f16 Bs[128*128];
  int Mbase = mb*128;
  for (int p = 0; p < 8; ++p) {
    int c = p*256 + t; int row = c >> 4, ci = c & 15;
    int sw = (ci ^ (row & 15)) * 8;
    *(f16x8*)&As[row*128 + sw] = *(const f16x8*)&xn[(size_t)(Mbase + row)*CIN + ci*8];
    *(f16x8*)&Bs[row*128 + sw] = *(const f16x8*)&W4T[(size_t)(nb*128 + row)*CIN + ci*8];
  }
  __syncthreads();
  int m0 = wave*32;
  f16x8 af[2][4];
#pragma unroll
  for (int mt = 0; mt < 2; ++mt)
#pragma unroll
    for (int kt = 0; kt < 4; ++kt)
      af[mt][kt] = *(const f16x8*)&As[(m0 + mt*16 + l15)*128 + ((kt*4 + quad) ^ l15)*8];
  int i = mb/3, j0 = (mb - (mb/3)*3)*128 + m0;
#pragma unroll
  for (int ct = 0; ct < 8; ++ct) {
    f32x4 acc0 = (f32x4){0,0,0,0}, acc1 = (f32x4){0,0,0,0};
#pragma unroll
    for (int kt = 0; kt < 4; ++kt) {
      f16x8 bf = *(const f16x8*)&Bs[(ct*16 + l15)*128 + ((kt*4 + quad) ^ l15)*8];
      acc0 = MFMA_16x16x32(af[0][kt], bf, acc0);
      acc1 = MFMA_16x16x32(af[1][kt], bf, acc1);
    }
    int col = nb*128 + ct*16 + l15;
    int cc = col & 127;
    int hh = cc >> 5, d = cc & 31;
    if (nb == 3) {
      float bgv = bg[cc];
#pragma unroll
      for (int mt = 0; mt < 2; ++mt) {
        f32x4 a = mt ? acc1 : acc0;
#pragma unroll
        for (int r = 0; r < 4; ++r) {
          int jj = j0 + mt*16 + quad*4 + r;
          float sg = 1.0f/(1.0f + __expf(-(a[r] + bgv)));
          gb[(size_t)(i*NSEQ + jj)*CIN + cc] = (f16)sg;
        }
      }
    } else {
      f16* dstb = nb==0 ? qb : (nb==1 ? kb : vb);
      float scale = nb==0 ? 0.25503576722f : 1.0f;   // log2e / sqrt(32)
#pragma unroll
      for (int mt = 0; mt < 2; ++mt) {
        f32x4 a = mt ? acc1 : acc0;
#pragma unroll
        for (int r = 0; r < 4; ++r) {
          int jj = j0 + mt*16 + quad*4 + r;
          dstb[((size_t)(i*NH + hh)*NSEQ + jj)*DHD + d] = (f16)(a[r]*scale);
        }
      }
    }
  }
}

// ---------------- attention v3: NO LDS, no barriers. One block per (h, i) (h-outer for L2 bias
// locality). K/V/bias frags straight from global (L2-hit). exp2-based softmax (scales pre-folded).
__global__ __launch_bounds__(256, 4) void k_attn(const f16* __restrict__ qg, const f16* __restrict__ kg,
    const f16* __restrict__ vg, const float* __restrict__ bias4, f16* __restrict__ og) {
  int b = blockIdx.x; int h = b / NSEQ; int i = b - h*NSEQ;
  int t = threadIdx.x; int wave = t >> 6; int lane = t & 63;
  int l15 = lane & 15, quad = lane >> 4;
  size_t base = (size_t)(i*NH + h) * NSEQ * DHD;
  int qt0 = wave*6;
  f16x8 qf[6];
#pragma unroll
  for (int s = 0; s < 6; ++s)
    qf[s] = *(const f16x8*)&qg[base + (size_t)((qt0+s)*16 + l15)*DHD + quad*8];
  f32x4 oa[6][2];
  float lsum[6];
#pragma unroll
  for (int s = 0; s < 6; ++s) { lsum[s] = 0.f; oa[s][0] = (f32x4){0,0,0,0}; oa[s][1] = (f32x4){0,0,0,0}; }
  const f16* kp = kg + base + (size_t)l15*DHD + quad*8;
  const f16* vp = vg + base + (size_t)(quad*4)*DHD + l15;
  const float* bp = bias4 + (((size_t)h*96 + quad)*NSEQ + qt0*16 + l15)*4;
  for (int kt = 0; kt < 24; ++kt) {
    f16x8 kf = *(const f16x8*)kp;
    f16x4 vf0, vf1;
#pragma unroll
    for (int jj = 0; jj < 4; ++jj) { vf0[jj] = vp[jj*DHD]; vf1[jj] = vp[jj*DHD + 16]; }
    f32x4 cb[6];
#pragma unroll
    for (int s = 0; s < 6; ++s) cb[s] = *(const f32x4*)(bp + s*64);
    kp += 16*DHD; vp += 16*DHD; bp += 4*NSEQ*4;
#pragma unroll
    for (int s = 0; s < 6; ++s) {
      f32x4 st = MFMA_16x16x32(kf, qf[s], cb[s]);   // S^T tile: row=k, col=q (bias via C-init)
      float p0 = __builtin_amdgcn_exp2f(st[0]);
      float p1 = __builtin_amdgcn_exp2f(st[1]);
      float p2 = __builtin_amdgcn_exp2f(st[2]);
      float p3 = __builtin_amdgcn_exp2f(st[3]);
      lsum[s] += (p0 + p1) + (p2 + p3);
      f16x4 pa; pa[0]=(f16)p0; pa[1]=(f16)p1; pa[2]=(f16)p2; pa[3]=(f16)p3;
      oa[s][0] = MFMA_16x16x16(pa, vf0, oa[s][0]);  // C-layout of S^T == A-layout for K=16 MFMA
      oa[s][1] = MFMA_16x16x16(pa, vf1, oa[s][1]);
    }
  }
#pragma unroll
  for (int s = 0; s < 6; ++s) {
    float lf = lsum[s];
    lf += __shfl_xor(lf, 16);
    lf += __shfl_xor(lf, 32);
    float inv = 1.0f / lf;   // valid for q = l15
#pragma unroll
    for (int r = 0; r < 4; ++r) {
      float invr = __shfl(inv, quad*4 + r);
      int qrow = (qt0+s)*16 + quad*4 + r;
      size_t ob = (size_t)(i*NSEQ + qrow)*(NH*DHD) + h*DHD;
      og[ob + l15]      = (f16)(oa[s][0][r] * invr);
      og[ob + 16 + l15] = (f16)(oa[s][1][r] * invr);
    }
  }
}

// ---------------- final: out = (g*o) @ Wo + bo  (fp32 out)
__global__ __launch_bounds__(256) void k_final(const f16* __restrict__ gb, const f16* __restrict__ ob,
    const f16* __restrict__ WoT, const float* __restrict__ bo, float* __restrict__ out) {
  int mb = blockIdx.x;
  int t = threadIdx.x, wave = t >> 6, lane = t & 63;
  int l15 = lane & 15, quad = lane >> 4;
  __shared__ __align__(16) f16 As[128*128];
  __shared__ __align__(16) f16 Bs[128*128];
  int Mbase = mb*128;
  for (int p = 0; p < 8; ++p) {
    int c = p*256 + t; int row = c >> 4, ci = c & 15;
    int sw = (ci ^ (row & 15)) * 8;
    f16x8 gv = *(const f16x8*)&gb[(size_t)(Mbase + row)*CIN + ci*8];
    f16x8 ov = *(const f16x8*)&ob[(size_t)(Mbase + row)*CIN + ci*8];
    *(f16x8*)&As[row*128 + sw] = gv*ov;
    *(f16x8*)&Bs[row*128 + sw] = *(const f16x8*)&WoT[row*CIN + ci*8];
  }
  __syncthreads();
  int m0 = wave*32;
  f16x8 af[2][4];
#pragma unroll
  for (int mt = 0; mt < 2; ++mt)
#pragma unroll
    for (int kt = 0; kt < 4; ++kt)
      af[mt][kt] = *(const f16x8*)&As[(m0 + mt*16 + l15)*128 + ((kt*4 + quad) ^ l15)*8];
#pragma unroll
  for (int ct = 0; ct < 8; ++ct) {
    f32x4 acc0 = (f32x4){0,0,0,0}, acc1 = (f32x4){0,0,0,0};
#pragma unroll
    for (int kt = 0; kt < 4; ++kt) {
      f16x8 bf = *(const f16x8*)&Bs[(ct*16 + l15)*128 + ((kt*4 + quad) ^ l15)*8];
      acc0 = MFMA_16x16x32(af[0][kt], bf, acc0);
      acc1 = MFMA_16x16x32(af[1][kt], bf, acc1);
    }
    float bov = bo[ct*16 + l15];
#pragma unroll
    for (int mt = 0; mt < 2; ++mt) {
      f32x4 a = mt ? acc1 : acc0;
#pragma unroll
      for (int r = 0; r < 4; ++r) {
        int mrow = Mbase + m0 + mt*16 + quad*4 + r;
        out[(size_t)mrow*CIN + ct*16 + l15] = a[r] + bov;
      }
    }
  }
}

extern "C" void kernel_launch(void* const* d_in, const int* in_sizes, int n_in,
                              void* d_out, int out_size, void* d_ws, size_t ws_size,
                              hipStream_t stream) {
  (void)in_sizes; (void)n_in; (void)out_size; (void)ws_size;
  const float* x    = (const float*)d_in[0];
  const float* sinp = (const float*)d_in[1];
  const float* gam  = (const float*)d_in[2];
  const float* bet  = (const float*)d_in[3];
  const float* Wq1  = (const float*)d_in[4];
  const float* Wq2  = (const float*)d_in[5];
  const float* Wq3  = (const float*)d_in[6];
  const float* Wk1  = (const float*)d_in[7];
  const float* Wk2  = (const float*)d_in[8];
  const float* Wk3  = (const float*)d_in[9];
  const float* Wqa  = (const float*)d_in[10];
  const float* Wka  = (const float*)d_in[11];
  const float* Wva  = (const float*)d_in[12];
  const float* Wg   = (const float*)d_in[13];
  const float* bg   = (const float*)d_in[14];
  const float* Wo   = (const float*)d_in[15];
  const float* bo   = (const float*)d_in[16];
  float* out = (float*)d_out;

  char* w = (char*)d_ws;
  auto carve = [&](size_t bytes) { char* p = w; w += (bytes + 255) & ~(size_t)255; return p; };
  f16*   xn    = (f16*)carve((size_t)NN*CIN*2);    // reused as o after k_proj
  f16*   qb    = (f16*)carve((size_t)NN*CIN*2);
  f16*   kb    = (f16*)carve((size_t)NN*CIN*2);
  f16*   vb    = (f16*)carve((size_t)NN*CIN*2);
  f16*   gbuf  = (f16*)carve((size_t)NN*CIN*2);
  float* bias4 = (float*)carve((size_t)NH*NSEQ*NSEQ*4);
  float* rowm  = (float*)carve((size_t)NSEQ*CIN*4);
  float* colm  = (float*)carve((size_t)NSEQ*CIN*4);
  float* qbT   = (float*)carve((size_t)(NH*RNK)*NSEQ*4);
  float* kbT   = (float*)carve((size_t)(NH*RNK)*NSEQ*4);
  f16*   W4T   = (f16*)carve((size_t)512*CIN*2);
  f16*   WoT   = (f16*)carve((size_t)CIN*CIN*2);
  f16*   wmlp  = (f16*)carve((size_t)WMLP_TOT*2);
  f16*   obuf  = xn;

  hipMemsetAsync(rowm, 0, (size_t)NSEQ*CIN*4, stream);
  k_convert<<<320, 256, 0, stream>>>(Wqa, Wka, Wva, Wg, Wo, W4T, WoT);
  k_convert2<<<WMLP_TOT/256, 256, 0, stream>>>(Wq1, Wq2, Wq3, Wk1, Wk2, Wk3, wmlp);
  k_ln<<<NSEQ*4, 256, 0, stream>>>(x, gam, bet, xn, rowm);
  k_colmean<<<NSEQ, 256, 0, stream>>>(xn, colm);
  k_mlp2<<<24, 256, 0, stream>>>(rowm, colm, sinp, wmlp, qbT, kbT);
  k_bias<<<NH*96, 128, 0, stream>>>(qbT, kbT, bias4);
  k_proj<<<4608, 256, 0, stream>>>(xn, W4T, bg, qb, kb, vb, gbuf);
  k_attn<<<NH*NSEQ, 256, 0, stream>>>(qb, kb, vb, bias4, obuf);
  k_final<<<1152, 256, 0, stream>>>(gbuf, obuf, WoT, bo, out);
}